// Round 18
// baseline (690.837 us; speedup 1.0000x reference)
//
#include <hip/hip_runtime.h>
#include <cfloat>
#include <cmath>

#define T_    2048
#define HID_  2048
#define QKVN_ 2112
#define QKVX_ 2272   // fused: 2112 qkv | 128 ki | 32 wgt
#define QLR_  1536
#define KVLR_ 512
#define ROPE_ 64
#define NOPE_ 128
#define QKD_  192
#define VD_   128
#define H_    16
#define IDXH_ 32
#define IDXD_ 128
#define TOPK_ 512
#define EPS_  1e-6f
#define SCALING_ 0.07216878364870323f   // 192^-0.5

typedef unsigned int u32;
typedef unsigned short u16;
typedef __bf16 bf16x8 __attribute__((ext_vector_type(8)));
typedef _Float16 f16;
typedef f16 f16x8 __attribute__((ext_vector_type(8)));
typedef float f32x4 __attribute__((ext_vector_type(4)));

__device__ __forceinline__ u16 f2bf(float x) {
  u32 u = __float_as_uint(x);
  u32 r = (u + 0x7fffu + ((u >> 16) & 1u)) >> 16;
  return (u16)r;
}
__device__ __forceinline__ float bf2f(u16 h) { return __uint_as_float(((u32)h) << 16); }
__device__ __forceinline__ u32 pack2(float a, float b) { return (u32)f2bf(a) | ((u32)f2bf(b) << 16); }
__device__ __forceinline__ bf16x8 ld8(const void* p) { return *(const bf16x8*)p; }
__device__ __forceinline__ f32x4 mfma16(bf16x8 a, bf16x8 b, f32x4 c) {
  return __builtin_amdgcn_mfma_f32_16x16x32_bf16(a, b, c, 0, 0, 0);
}
__device__ __forceinline__ u16 hbits(f16 h) { union { f16 h; u16 u; } c; c.h = h; return c.u; }
__device__ __forceinline__ u32 hpack(f16 a, f16 b) { return (u32)hbits(a) | ((u32)hbits(b) << 16); }
__device__ __forceinline__ f16x8 ldh8(const void* p) { return *(const f16x8*)p; }
__device__ __forceinline__ f32x4 mfmah(f16x8 a, f16x8 b, f32x4 c) {
  return __builtin_amdgcn_mfma_f32_16x16x32_f16(a, b, c, 0, 0, 0);
}
__device__ __forceinline__ void gload16(const u16* g, u16* l) {
  __builtin_amdgcn_global_load_lds(
      (__attribute__((address_space(1))) void*)(g),
      (__attribute__((address_space(3))) void*)(l), 16, 0, 0);
}

// ---------------------------------------------------------------- rope table
__global__ __launch_bounds__(256) void rope_tab_kernel(float2* __restrict__ tab) {
  int i = blockIdx.x * 256 + threadIdx.x;
  if (i >= T_ * 32) return;
  int t = i >> 5, j = i & 31;
  float inv = powf(10000.f, -(float)j * (1.f / 32.f));
  float f = (float)t * inv;
  tab[i] = make_float2(cosf(f), sinf(f));
}
__device__ __forceinline__ void rope_apply(float2 cs, float& x0, float& x1) {
  float a = x0, b = x1;
  x0 = a * cs.x - b * cs.y;
  x1 = a * cs.y + b * cs.x;
}

// ---------------------------------------------------------------- prep (multi-job)
struct TSJob { const float* src; u16* oh; u16* ol; int K; int N; };
__global__ __launch_bounds__(256) void transpose_split_multi(
    TSJob j0, TSJob j1, TSJob j2, TSJob j3) {
  TSJob jb = (blockIdx.z == 0) ? j0 : (blockIdx.z == 1) ? j1 : (blockIdx.z == 2) ? j2 : j3;
  int k0 = blockIdx.y * 64, n0 = blockIdx.x * 64;
  if (k0 >= jb.K || n0 >= jb.N) return;
  __shared__ float t[64][65];
  for (int j = 0; j < 16; ++j) {
    int u = threadIdx.x + 256 * j; int r = u >> 6, c = u & 63;
    t[r][c] = (k0 + r < jb.K && n0 + c < jb.N) ? jb.src[(size_t)(k0 + r) * jb.N + n0 + c] : 0.f;
  }
  __syncthreads();
  for (int j = 0; j < 16; ++j) {
    int u = threadIdx.x + 256 * j; int r = u >> 6, c = u & 63;
    if (n0 + r < jb.N && k0 + c < jb.K) {
      float v = t[c][r];
      f16 h = (f16)v;
      jb.oh[(size_t)(n0 + r) * jb.K + k0 + c] = hbits(h);
      jb.ol[(size_t)(n0 + r) * jb.K + k0 + c] = hbits((f16)(v - (float)h));
    }
  }
}

struct TBJob { const float* src; u16* out; int K; int N; };
__global__ __launch_bounds__(256) void transpose_bf16_multi(TBJob j0, TBJob j1, TBJob j2) {
  TBJob jb = (blockIdx.z == 0) ? j0 : (blockIdx.z == 1) ? j1 : j2;
  int k0 = blockIdx.y * 64, n0 = blockIdx.x * 64;
  if (k0 >= jb.K || n0 >= jb.N) return;
  __shared__ float t[64][65];
  for (int j = 0; j < 16; ++j) {
    int u = threadIdx.x + 256 * j; int r = u >> 6, c = u & 63;
    t[r][c] = (k0 + r < jb.K && n0 + c < jb.N) ? jb.src[(size_t)(k0 + r) * jb.N + n0 + c] : 0.f;
  }
  __syncthreads();
  for (int j = 0; j < 16; ++j) {
    int u = threadIdx.x + 256 * j; int r = u >> 6, c = u & 63;
    if (n0 + r < jb.N && k0 + c < jb.K) jb.out[(size_t)(n0 + r) * jb.K + k0 + c] = f2bf(t[c][r]);
  }
}

__global__ __launch_bounds__(256) void split_f16_k(
    const float* __restrict__ in, u16* __restrict__ hi, u16* __restrict__ lo, long n) {
  for (long i = ((long)blockIdx.x * 256 + threadIdx.x) * 4; i < n; i += (long)gridDim.x * 1024) {
    float4 v = *(const float4*)(in + i);
    f16 a = (f16)v.x, b = (f16)v.y, c = (f16)v.z, d = (f16)v.w;
    *(u32*)(hi + i) = hpack(a, b);
    *(u32*)(hi + i + 2) = hpack(c, d);
    *(u32*)(lo + i) = hpack((f16)(v.x - (float)a), (f16)(v.y - (float)b));
    *(u32*)(lo + i + 2) = hpack((f16)(v.z - (float)c), (f16)(v.w - (float)d));
  }
}

__global__ __launch_bounds__(256) void conv_bf16_k(
    const float* __restrict__ in, u16* __restrict__ out, long n) {
  for (long i = ((long)blockIdx.x * 256 + threadIdx.x) * 4; i < n; i += (long)gridDim.x * 1024) {
    float4 v = *(const float4*)(in + i);
    *(u32*)(out + i) = pack2(v.x, v.y);
    *(u32*)(out + i + 2) = pack2(v.z, v.w);
  }
}

// ---------------------------------------------------------------- strict GEMM (DMA-staged hi/lo)
__global__ __launch_bounds__(256) void gemm_hl(
    const u16* __restrict__ Ah_, const u16* __restrict__ Al_, int lda,
    const u16* __restrict__ Bh_, const u16* __restrict__ Bl_, int ldb,
    float* __restrict__ C, int ldc, const float* __restrict__ bias, int bcol0,
    float bscale, int N, int K) {
  __shared__ u32 Ah[128][16], Al[128][16], Bh[128][16], Bl[128][16];
  const int tid = threadIdx.x;
  const int bm = blockIdx.y * 128, bn = blockIdx.x * 128;
  const int wid = tid >> 6, lane = tid & 63, wr = wid >> 1, wc = wid & 1;
  const int lr = lane & 15, lg = lane >> 4;
  const u16* srcb = (wid == 0) ? Ah_ : (wid == 1) ? Al_ : (wid == 2) ? Bh_ : Bl_;
  const int sld = (wid < 2) ? lda : ldb;
  const int rb = (wid < 2) ? bm : bn;
  u16* dst = (u16*)((wid == 0) ? &Ah[0][0] : (wid == 1) ? &Al[0][0]
                                           : (wid == 2) ? &Bh[0][0] : &Bl[0][0]);
  const int rowl = lane >> 2;
  const int offl = (lane & 3) * 8;
  f32x4 acc[4][4] = {};
  for (int k0 = 0; k0 < K; k0 += 32) {
#pragma unroll
    for (int c = 0; c < 8; ++c) {
      int gr = rb + c * 16 + rowl;
      if (wid >= 2) gr = min(gr, N - 1);
      gload16(srcb + (size_t)gr * sld + k0 + offl, dst + c * 512);
    }
    __syncthreads();
    f16x8 ah[4], al[4], bh[4], bl[4];
#pragma unroll
    for (int i = 0; i < 4; ++i) {
      ah[i] = ldh8(&Ah[wr * 64 + i * 16 + lr][lg * 4]);
      al[i] = ldh8(&Al[wr * 64 + i * 16 + lr][lg * 4]);
      bh[i] = ldh8(&Bh[wc * 64 + i * 16 + lr][lg * 4]);
      bl[i] = ldh8(&Bl[wc * 64 + i * 16 + lr][lg * 4]);
    }
#pragma unroll
    for (int i = 0; i < 4; ++i)
#pragma unroll
      for (int jn = 0; jn < 4; ++jn) {
        acc[i][jn] = mfmah(ah[i], bh[jn], acc[i][jn]);
        acc[i][jn] = mfmah(ah[i], bl[jn], acc[i][jn]);
        acc[i][jn] = mfmah(al[i], bh[jn], acc[i][jn]);
      }
    __syncthreads();
  }
#pragma unroll
  for (int i = 0; i < 4; ++i)
#pragma unroll
    for (int jn = 0; jn < 4; ++jn)
#pragma unroll
      for (int j = 0; j < 4; ++j) {
        int row = bm + wr * 64 + i * 16 + lg * 4 + j;
        int col = bn + wc * 64 + jn * 16 + lr;
        if (col < N) {
          float v = acc[i][jn][j];
          if (col >= bcol0) v = (v + bias[col - bcol0]) * bscale;
          C[(size_t)row * ldc + col] = v;
        }
      }
}

// ---------------------------------------------------------------- tolerant bf16 GEMM (DMA-staged)
template <int CBF16>
__global__ __launch_bounds__(256) void gemm_t(
    const u16* __restrict__ Ab, int lda, long aoz,
    const u16* __restrict__ Bt, int ldb, long boz,
    void* __restrict__ Cp, int ldc, long coz, int N, int K) {
  __shared__ u32 As[128][16], Bs[128][16];
  const int tid = threadIdx.x;
  const int z = blockIdx.z;
  const int bm = blockIdx.y * 128, bn = blockIdx.x * 128;
  const int wid = tid >> 6, lane = tid & 63, wr = wid >> 1, wc = wid & 1;
  const int lr = lane & 15, lg = lane >> 4;
  const u16* A = Ab + aoz * z;
  const u16* B = Bt + boz * z;
  const u16* srcb = (wid < 2) ? A : B;
  const int sld = (wid < 2) ? lda : ldb;
  const int rb = (wid < 2) ? bm : bn;
  u16* dst = (u16*)((wid < 2) ? &As[0][0] : &Bs[0][0]);
  const int ccb = (wid & 1) * 4;
  const int rowl = lane >> 2;
  const int offl = (lane & 3) * 8;
  f32x4 acc[4][4] = {};
  for (int k0 = 0; k0 < K; k0 += 32) {
#pragma unroll
    for (int c = 0; c < 4; ++c) {
      int cc = ccb + c;
      int gr = rb + cc * 16 + rowl;
      if (wid >= 2) gr = min(gr, N - 1);
      gload16(srcb + (size_t)gr * sld + k0 + offl, dst + cc * 512);
    }
    __syncthreads();
    bf16x8 af[4], bf[4];
#pragma unroll
    for (int i = 0; i < 4; ++i) {
      af[i] = ld8(&As[wr * 64 + i * 16 + lr][lg * 4]);
      bf[i] = ld8(&Bs[wc * 64 + i * 16 + lr][lg * 4]);
    }
#pragma unroll
    for (int i = 0; i < 4; ++i)
#pragma unroll
      for (int jn = 0; jn < 4; ++jn)
        acc[i][jn] = mfma16(af[i], bf[jn], acc[i][jn]);
    __syncthreads();
  }
#pragma unroll
  for (int i = 0; i < 4; ++i)
#pragma unroll
    for (int jn = 0; jn < 4; ++jn)
#pragma unroll
      for (int j = 0; j < 4; ++j) {
        int row = bm + wr * 64 + i * 16 + lg * 4 + j;
        int col = bn + wc * 64 + jn * 16 + lr;
        if (col < N) {
          if (CBF16) ((u16*)Cp)[coz * z + (size_t)row * ldc + col] = f2bf(acc[i][jn][j]);
          else ((float*)Cp)[coz * z + (size_t)row * ldc + col] = acc[i][jn][j];
        }
      }
}

// ---------------------------------------------------------------- RMS norms (q_cn -> f16 hi/lo + bf16)
__global__ __launch_bounds__(256) void rmsnorm_kernel(
    const float* __restrict__ qkvx, const float* __restrict__ qw,
    const float* __restrict__ kvw, u16* __restrict__ qcb,
    u16* __restrict__ qch, u16* __restrict__ qcl, u16* __restrict__ kv_cn) {
  const int t = blockIdx.x, tid = threadIdx.x;
  const float* row = qkvx + (size_t)t * QKVX_;
  __shared__ float red[256];
  float ss = 0.f;
  for (int i = tid; i < QLR_; i += 256) { float v = row[i]; ss += v * v; }
  red[tid] = ss; __syncthreads();
  for (int s = 128; s; s >>= 1) { if (tid < s) red[tid] += red[tid + s]; __syncthreads(); }
  float scl = 1.0f / sqrtf(red[0] / (float)QLR_ + EPS_);
  for (int i = tid; i < QLR_; i += 256) {
    float val = row[i] * scl * qw[i];
    qcb[(size_t)t * QLR_ + i] = f2bf(val);
    f16 h = (f16)val;
    qch[(size_t)t * QLR_ + i] = hbits(h);
    qcl[(size_t)t * QLR_ + i] = hbits((f16)(val - (float)h));
  }
  __syncthreads();
  ss = 0.f;
  for (int i = tid; i < KVLR_; i += 256) { float v = row[QLR_ + i]; ss += v * v; }
  red[tid] = ss; __syncthreads();
  for (int s = 128; s; s >>= 1) { if (tid < s) red[tid] += red[tid + s]; __syncthreads(); }
  scl = 1.0f / sqrtf(red[0] / (float)KVLR_ + EPS_);
  for (int i = tid; i < KVLR_; i += 256)
    kv_cn[(size_t)t * KVLR_ + i] = f2bf(row[QLR_ + i] * scl * kvw[i]);
}

// ---------------------------------------------------------------- rope users (table-driven)
__global__ __launch_bounds__(256) void rope_qi_split_kernel(
    const float* __restrict__ qi, const float2* __restrict__ tab,
    u16* __restrict__ qih, u16* __restrict__ qil) {
  const int t = blockIdx.x, tid = threadIdx.x;
  const float* src = qi + (size_t)t * (IDXH_ * IDXD_);
  u16* dh = qih + (size_t)t * (IDXH_ * IDXD_);
  u16* dl = qil + (size_t)t * (IDXH_ * IDXD_);
  for (int p = tid; p < IDXH_ * IDXD_ / 2; p += 256) {
    int d = p & 63;
    float x0 = src[2 * p], x1 = src[2 * p + 1];
    if (d < 32) rope_apply(tab[t * 32 + d], x0, x1);
    f16 h0 = (f16)x0, h1 = (f16)x1;
    *(u32*)(dh + 2 * p) = hpack(h0, h1);
    *(u32*)(dl + 2 * p) = hpack((f16)(x0 - (float)h0), (f16)(x1 - (float)h1));
  }
}

__global__ __launch_bounds__(256) void rope_q_bf_kernel(
    u16* __restrict__ qfb, const float2* __restrict__ tab) {
  const int t = blockIdx.x, tid = threadIdx.x;
  for (int idx = tid; idx < H_ * 32; idx += 256) {
    int hh = idx / 32, j = idx % 32;
    u16* p = qfb + (size_t)t * (H_ * QKD_) + hh * QKD_ + NOPE_ + 2 * j;
    float x0 = bf2f(p[0]), x1 = bf2f(p[1]);
    rope_apply(tab[t * 32 + j], x0, x1);
    p[0] = f2bf(x0); p[1] = f2bf(x1);
  }
}

__global__ __launch_bounds__(64) void rope_kpe_kernel(
    const float* __restrict__ qkvx, const float2* __restrict__ tab,
    u16* __restrict__ kper) {
  const int t = blockIdx.x, tid = threadIdx.x;
  if (tid >= 32) return;
  const float* p = qkvx + (size_t)t * QKVX_ + (QLR_ + KVLR_);
  float x0 = p[2 * tid], x1 = p[2 * tid + 1];
  rope_apply(tab[t * 32 + tid], x0, x1);
  kper[(size_t)t * ROPE_ + 2 * tid] = f2bf(x0);
  kper[(size_t)t * ROPE_ + 2 * tid + 1] = f2bf(x1);
}

__global__ __launch_bounds__(128) void ki_ln_rope_kernel(
    const float* __restrict__ qkvx, const float* __restrict__ gamma,
    const float* __restrict__ beta, const float2* __restrict__ tab,
    u16* __restrict__ kih, u16* __restrict__ kil) {
  const int t = blockIdx.x, tid = threadIdx.x;
  __shared__ float x[128];
  __shared__ float red[128];
  float v = qkvx[(size_t)t * QKVX_ + QKVN_ + tid];
  red[tid] = v; __syncthreads();
  for (int s = 64; s; s >>= 1) { if (tid < s) red[tid] += red[tid + s]; __syncthreads(); }
  float mu = red[0] / 128.f;
  __syncthreads();
  float d = v - mu;
  red[tid] = d * d; __syncthreads();
  for (int s = 64; s; s >>= 1) { if (tid < s) red[tid] += red[tid + s]; __syncthreads(); }
  float var = red[0] / 128.f;
  float y = d * (1.0f / sqrtf(var + EPS_)) * gamma[tid] + beta[tid];
  x[tid] = y; __syncthreads();
  if (tid < 32) {
    float x0 = x[2 * tid], x1 = x[2 * tid + 1];
    rope_apply(tab[t * 32 + tid], x0, x1);
    x[2 * tid] = x0; x[2 * tid + 1] = x1;
  }
  __syncthreads();
  float fv = x[tid];
  f16 h = (f16)fv;
  kih[(size_t)t * IDXD_ + tid] = hbits(h);
  kil[(size_t)t * IDXD_ + tid] = hbits((f16)(fv - (float)h));
}

// ---------------------------------------------------------------- indexer score (DMA-staged, swizzled)
// LDS tiles [64][64] u32 unpadded; LDS[row][c] = src[c ^ ((row&7)<<2)] (u32 units),
// realized by per-lane source permutation; reads XOR the same term -> bit-identical.
__global__ __launch_bounds__(256) void score_mfma(
    const u16* __restrict__ qih, const u16* __restrict__ qil,
    const u16* __restrict__ kih, const u16* __restrict__ kil,
    const float* __restrict__ wgt, int ldw, float* __restrict__ score) {
  const int s0 = blockIdx.x * 64, t0 = blockIdx.y * 64;
  if (s0 > t0 + 63) return;
  __shared__ u32 Kh[64][64], Kl[64][64], Qh[64][64], Ql[64][64];
  __shared__ float wts[64][33];
  const int tid = threadIdx.x;
  const int wid = tid >> 6, lane = tid & 63, wr = wid >> 1, wc = wid & 1;
  const int lr = lane & 15, lg = lane >> 4;
  // staging geometry: each gload16 call covers 4 rows (64 lanes x 16B = 4 x 128-u16 rows)
  const int rl = lane >> 4;             // row within call (0..3)
  const int bcol = (lane & 15) * 8;     // base src col (u16)
  // stage K tiles (once) via DMA, swizzled source
#pragma unroll
  for (int c = 0; c < 4; ++c) {
    int row = wid * 16 + c * 4 + rl;
    int sc = bcol ^ ((row & 7) << 3);
    gload16(kih + (size_t)(s0 + row) * IDXD_ + sc, (u16*)&Kh[wid * 16 + c * 4][0]);
    gload16(kil + (size_t)(s0 + row) * IDXD_ + sc, (u16*)&Kl[wid * 16 + c * 4][0]);
  }
#pragma unroll
  for (int j = 0; j < 8; ++j) {
    int u = tid + 256 * j; int r = u >> 5, c = u & 31;
    wts[r][c] = wgt[(size_t)(t0 + r) * ldw + c];
  }
  __syncthreads();
  const int rswz = (lr & 7) << 2;       // read-side XOR (u32 units), row&7 == lr&7
  f16x8 bh[2][4], bl[2][4];
#pragma unroll
  for (int ni = 0; ni < 2; ++ni)
#pragma unroll
    for (int kb = 0; kb < 4; ++kb) {
      bh[ni][kb] = ldh8(&Kh[wc * 32 + ni * 16 + lr][(kb * 16 + lg * 4) ^ rswz]);
      bl[ni][kb] = ldh8(&Kl[wc * 32 + ni * 16 + lr][(kb * 16 + lg * 4) ^ rswz]);
    }
  f32x4 fin[2][2] = {};
  for (int h = 0; h < IDXH_; ++h) {
#pragma unroll
    for (int c = 0; c < 4; ++c) {
      int row = wid * 16 + c * 4 + rl;
      int sc = bcol ^ ((row & 7) << 3);
      size_t g = (size_t)(t0 + row) * (IDXH_ * IDXD_) + h * IDXD_ + sc;
      gload16(qih + g, (u16*)&Qh[wid * 16 + c * 4][0]);
      gload16(qil + g, (u16*)&Ql[wid * 16 + c * 4][0]);
    }
    __syncthreads();
    f32x4 acch[2][2] = {};
#pragma unroll
    for (int kb = 0; kb < 4; ++kb) {
      f16x8 ah0 = ldh8(&Qh[wr * 32 + lr][(kb * 16 + lg * 4) ^ rswz]);
      f16x8 ah1 = ldh8(&Qh[wr * 32 + 16 + lr][(kb * 16 + lg * 4) ^ rswz]);
      f16x8 al0 = ldh8(&Ql[wr * 32 + lr][(kb * 16 + lg * 4) ^ rswz]);
      f16x8 al1 = ldh8(&Ql[wr * 32 + 16 + lr][(kb * 16 + lg * 4) ^ rswz]);
#pragma unroll
      for (int ni = 0; ni < 2; ++ni) {
        acch[0][ni] = mfmah(ah0, bh[ni][kb], acch[0][ni]);
        acch[0][ni] = mfmah(ah0, bl[ni][kb], acch[0][ni]);
        acch[0][ni] = mfmah(al0, bh[ni][kb], acch[0][ni]);
        acch[1][ni] = mfmah(ah1, bh[ni][kb], acch[1][ni]);
        acch[1][ni] = mfmah(ah1, bl[ni][kb], acch[1][ni]);
        acch[1][ni] = mfmah(al1, bh[ni][kb], acch[1][ni]);
      }
    }
#pragma unroll
    for (int mi = 0; mi < 2; ++mi)
#pragma unroll
      for (int j = 0; j < 4; ++j) {
        float w = wts[wr * 32 + mi * 16 + lg * 4 + j][h];
        fin[mi][0][j] += w * fmaxf(acch[mi][0][j], 0.f);
        fin[mi][1][j] += w * fmaxf(acch[mi][1][j], 0.f);
      }
    __syncthreads();
  }
#pragma unroll
  for (int mi = 0; mi < 2; ++mi)
#pragma unroll
    for (int ni = 0; ni < 2; ++ni)
#pragma unroll
      for (int j = 0; j < 4; ++j) {
        int row = t0 + wr * 32 + mi * 16 + lg * 4 + j;
        int col = s0 + wc * 32 + ni * 16 + lr;
        score[(size_t)row * T_ + col] = fin[mi][ni][j];
      }
}

// ---------------------------------------------------------------- top-k (exact, 8-bit radix)
__global__ __launch_bounds__(256) void topk_kernel(
    const float* __restrict__ score, int* __restrict__ selidx,
    int* __restrict__ selcnt) {
  const int t = blockIdx.x;
  const int L = t + 1;
  const int tid = threadIdx.x;
  if (L <= TOPK_) {
    for (int j = tid; j < TOPK_; j += 256)
      selidx[(size_t)t * TOPK_ + j] = (j < L) ? j : 0;
    if (tid == 0) selcnt[t] = L;
    return;
  }
  __shared__ unsigned u[T_];
  __shared__ unsigned hist[256];
  __shared__ unsigned sprefix;
  __shared__ int sk;
  __shared__ int part[256];
  for (int i = tid; i < T_; i += 256) {
    float v = (i < L) ? score[(size_t)t * T_ + i] : -FLT_MAX;
    unsigned b = __float_as_uint(v);
    u[i] = (b & 0x80000000u) ? ~b : (b | 0x80000000u);
  }
  if (tid == 0) { sprefix = 0u; sk = TOPK_; }
  __syncthreads();
  for (int pass = 0; pass < 4; ++pass) {
    const int shift = 24 - 8 * pass;
    hist[tid] = 0u;
    __syncthreads();
    unsigned pfx = sprefix;
    for (int i = tid; i < L; i += 256) {
      unsigned val = u[i];
      bool match = (pass == 0) || ((val >> (shift + 8)) == pfx);
      if (match) atomicAdd(&hist[(val >> shift) & 255u], 1u);
    }
    __syncthreads();
    if (tid == 0) {
      int k = sk; unsigned cum = 0u; int bsel = 0;
      for (int bb = 255; bb >= 0; --bb) {
        if (cum + hist[bb] >= (unsigned)k) { bsel = bb; sk = k - (int)cum; break; }
        cum += hist[bb];
      }
      sprefix = (sprefix << 8) | (unsigned)bsel;
    }
    __syncthreads();
  }
  const unsigned thr = sprefix;
  const int kEq = sk;
  const int base = tid * 8;
  int eqloc[8]; int esum = 0;
  for (int r = 0; r < 8; ++r) {
    int i = base + r;
    int f = (i < L && u[i] == thr) ? 1 : 0;
    eqloc[r] = esum; esum += f;
  }
  part[tid] = esum; __syncthreads();
  for (int off = 1; off < 256; off <<= 1) {
    int v = (tid >= off) ? part[tid - off] : 0;
    __syncthreads();
    part[tid] += v;
    __syncthreads();
  }
  const int ebase = (tid > 0) ? part[tid - 1] : 0;
  __syncthreads();
  int sloc[8], selflag[8]; int ssum = 0;
  for (int r = 0; r < 8; ++r) {
    int i = base + r;
    int f = 0;
    if (i < L) {
      unsigned ui = u[i];
      if (ui > thr) f = 1;
      else if (ui == thr && (ebase + eqloc[r]) < kEq) f = 1;
    }
    selflag[r] = f; sloc[r] = ssum; ssum += f;
  }
  part[tid] = ssum; __syncthreads();
  for (int off = 1; off < 256; off <<= 1) {
    int v = (tid >= off) ? part[tid - off] : 0;
    __syncthreads();
    part[tid] += v;
    __syncthreads();
  }
  const int sbase = (tid > 0) ? part[tid - 1] : 0;
  for (int r = 0; r < 8; ++r)
    if (selflag[r]) selidx[(size_t)t * TOPK_ + sbase + sloc[r]] = base + r;
  if (tid == 0) selcnt[t] = TOPK_;
}

// ---------------------------------------------------------------- MLA attention v8 (unchanged)
__global__ __launch_bounds__(256, 3) void attn_mla_kernel(
    const u16* __restrict__ qeff, const u16* __restrict__ qfb,
    const u16* __restrict__ kvcn, const u16* __restrict__ kper,
    const int* __restrict__ selidx, const int* __restrict__ selcnt,
    u16* __restrict__ Olat) {
  const int t = blockIdx.x;
  const int tid = threadIdx.x;
  const int wid = tid >> 6, lane = tid & 63;
  const int lr = lane & 15, lg = lane >> 4;
  __shared__ int sidxs[512];
  __shared__ u16 Pb[16][520];
  __shared__ __align__(16) u16 SB[4][4224];  // QK: 2 x 2048-u16 bufs; PV: u32[16][132]
  __shared__ float redm[4][16];
  __shared__ float reds[4][16];
  const int cnt = selcnt[t];
  for (int j = tid; j < 512; j += 256) sidxs[j] = selidx[(size_t)t * TOPK_ + j];
  __syncthreads();

  const int kl = lane >> 2;
  const int pcs = (((lane & 3) ^ ((lane >> 3) & 3))) << 3;
  const int rsw = ((lr >> 1) & 3) << 3;
  int skey[8];
#pragma unroll
  for (int j = 0; j < 8; ++j) skey[j] = sidxs[wid * 128 + j * 16 + kl];
  u16* buf0 = &SB[wid][0];
  u16* buf1 = &SB[wid][2048];

  const u16* qe = qeff + (size_t)t * (H_ * 512) + lr * 512 + lg * 8;
  const u16* qp = qfb + (size_t)t * (H_ * QKD_) + lr * QKD_ + NOPE_ + lg * 8;
  bf16x8 qf[18];
#pragma unroll
  for (int kb = 0; kb < 16; ++kb) qf[kb] = ld8(qe + kb * 32);
  qf[16] = ld8(qp);
  qf[17] = ld8(qp + 32);

  f32x4 lgv[8] = {};
#pragma unroll
  for (int j = 0; j < 4; ++j)
    gload16(kvcn + (size_t)skey[j] * 512 + pcs, buf0 + j * 512);
#pragma unroll
  for (int j = 0; j < 4; ++j)
    gload16(kvcn + (size_t)skey[4 + j] * 512 + pcs, buf1 + j * 512);
#pragma unroll
  for (int s = 0; s < 36; ++s) {
    const int kb = s >> 1, h = s & 1;
    u16* b = (h == 0) ? buf0 : buf1;
    if (s == 35) { asm volatile("s_waitcnt vmcnt(0)" ::: "memory"); }
    else         { asm volatile("s_waitcnt vmcnt(4)" ::: "memory"); }
    __builtin_amdgcn_sched_barrier(0);
    bf16x8 kf[4];
#pragma unroll
    for (int i = 0; i < 4; ++i)
      kf[i] = ld8(b + (i * 16 + lr) * 32 + (lg * 8 ^ rsw));
#pragma unroll
    for (int i = 0; i < 4; ++i)
      lgv[h * 4 + i] = mfma16(kf[i], qf[kb], lgv[h * 4 + i]);
    asm volatile("s_waitcnt lgkmcnt(0)" ::: "memory");
    __builtin_amdgcn_sched_barrier(0);
    if (s + 2 < 36) {
      const int kb2 = (s + 2) >> 1;
      if (kb2 < 16) {
#pragma unroll
        for (int j = 0; j < 4; ++j)
          gload16(kvcn + (size_t)skey[h * 4 + j] * 512 + kb2 * 32 + pcs, b + j * 512);
      } else {
#pragma unroll
        for (int j = 0; j < 4; ++j)
          gload16(kper + (size_t)skey[h * 4 + j] * 64 + (kb2 - 16) * 32 + pcs, b + j * 512);
      }
    }
  }

  float mx = -FLT_MAX;
#pragma unroll
  for (int m = 0; m < 8; ++m)
#pragma unroll
    for (int j = 0; j < 4; ++j) {
      int slot = wid * 128 + m * 16 + lg * 4 + j;
      float v = (slot < cnt) ? lgv[m][j] * SCALING_ : -FLT_MAX;
      lgv[m][j] = v;
      mx = fmaxf(mx, v);
    }
  mx = fmaxf(mx, __shfl_xor(mx, 16));
  mx = fmaxf(mx, __shfl_xor(mx, 32));
  if (lane < 16) redm[wid][lane] = mx;
  __syncthreads();
  float hm = fmaxf(fmaxf(redm[0][lr], redm[1][lr]), fmaxf(redm[2][lr], redm[3][lr]));
  float sm = 0.f;
#pragma unroll
  for (int m = 0; m < 8; ++m)
#pragma unroll
    for (int j = 0; j < 4; ++j) {
      int slot = wid * 128 + m * 16 + lg * 4 + j;
      float e = (slot < cnt) ? expf(lgv[m][j] - hm) : 0.f;
      lgv[m][j] = e; sm += e;
    }
  sm += __shfl_xor(sm, 16);
  sm += __shfl_xor(sm, 32);
  if (lane < 16) reds[wid][lane] = sm;
  __syncthreads();
  float inv = 1.f / (reds[0][lr] + reds[1][lr] + reds[2][lr] + reds[3][lr]);
#pragma unroll
  for (int m = 0; m < 8; ++m) {
    int sl = wid * 128 + m * 16 + lg * 4;
    *(u32*)&Pb[lr][sl] = pack2(lgv[m][0] * inv, lgv[m][1] * inv);
    *(u32*)&Pb[lr][sl + 2] = pack2(lgv[m][2] * inv, lgv[m][3] * inv);
  }
  __syncthreads();

  u32* vpw = (u32*)&SB[wid][0];
  const int pl = lane >> 4;
  const int gq = lane & 15;
  const u16* vsrc = kvcn + wid * 128 + gq * 8;
  f32x4 oacc[8] = {};
  uint4 ra[4], rb[4];
#pragma unroll
  for (int s = 0; s < 4; ++s) {
    int p = s * 4 + pl;
    ra[s] = *(const uint4*)(vsrc + (size_t)sidxs[2 * p] * 512);
    rb[s] = *(const uint4*)(vsrc + (size_t)sidxs[2 * p + 1] * 512);
  }
  for (int c = 0; c < 16; ++c) {
#pragma unroll
    for (int s = 0; s < 4; ++s) {
      int p = s * 4 + pl;
      int col = (gq * 8) ^ ((s & 3) << 3);
      const u16* A = (const u16*)&ra[s];
      const u16* B = (const u16*)&rb[s];
      u32 w[8];
#pragma unroll
      for (int j = 0; j < 8; ++j) w[j] = (u32)A[j] | ((u32)B[j] << 16);
      *(uint4*)&vpw[p * 132 + col] = make_uint4(w[0], w[1], w[2], w[3]);
      *(uint4*)&vpw[p * 132 + col + 4] = make_uint4(w[4], w[5], w[6], w[7]);
    }
    if (c < 15) {
#pragma unroll
      for (int s = 0; s < 4; ++s) {
        int p = s * 4 + pl;
        ra[s] = *(const uint4*)(vsrc + (size_t)sidxs[(c + 1) * 32 + 2 * p] * 512);
        rb[s] = *(const uint4*)(vsrc + (size_t)sidxs[(c + 1) * 32 + 2 * p + 1] * 512);
      }
    }
    bf16x8 pa = ld8(&Pb[lr][c * 32 + lg * 8]);
    union BB { u32 u[4]; bf16x8 v; };
    BB bb[8];
#pragma unroll
    for (int C = 0; C < 8; ++C) {
      int col = (C * 16 + lr) ^ (lg << 3);
#pragma unroll
      for (int e = 0; e < 4; ++e)
        bb[C].u[e] = vpw[(lg * 4 + e) * 132 + col];
    }
    __builtin_amdgcn_s_setprio(1);
#pragma unroll
    for (int C = 0; C < 8; ++C) oacc[C] = mfma16(pa, bb[C].v, oacc[C]);
    __builtin_amdgcn_s_setprio(0);
  }
#pragma unroll
  for (int C = 0; C < 8; ++C)
#pragma unroll
    for (int j = 0; j < 4; ++j) {
      int h = lg * 4 + j;
      Olat[(size_t)t * (H_ * 512) + h * 512 + wid * 128 + C * 16 + lr] = f2bf(oacc[C][j]);
    }
}

// ---------------------------------------------------------------- launch
extern "C" void kernel_launch(void* const* d_in, const int* in_sizes, int n_in,
                              void* d_out, int out_size, void* d_ws, size_t ws_size,
                              hipStream_t stream) {
  const float* hidden    = (const float*)d_in[1];
  const float* w_qkv_a   = (const float*)d_in[2];
  const float* q_a_ln_w  = (const float*)d_in[3];
  const float* w_qb      = (const float*)d_in[4];
  const float* kv_a_ln_w = (const float*)d_in[5];
  const float* w_kvb     = (const float*)d_in[6];
  const float* w_o       = (const float*)d_in[7];
  const float* w_idx_qb  = (const float*)d_in[8];
  const float* w_idx_k   = (const float*)d_in[9];
  const float* idx_g     = (const float*)d_in[10];
  const float* idx_b     = (const float*)d_in[11];
  const float* w_wproj   = (const float*)d_in[12];
  const float* b_wproj   = (const float*)d_in[13];

  char* W = (char*)d_ws;
  size_t o = 0;
  auto alloc = [&](size_t bytes) { void* p = W + o; o += (bytes + 255) & ~(size_t)255; return p; };
  u16* qcb     = (u16*)alloc((size_t)T_ * QLR_ * 2);
  u16* kv_cn   = (u16*)alloc((size_t)T_ * KVLR_ * 2);
  u16* kper    = (u16*)alloc((size_t)T_ * ROPE_ * 2);
  int* selidx  = (int*)alloc((size_t)T_ * TOPK_ * 4);
  int* selcnt  = (int*)alloc((size_t)T_ * 4);
  u16* kih     = (u16*)alloc((size_t)T_ * IDXD_ * 2);
  u16* kil     = (u16*)alloc((size_t)T_ * IDXD_ * 2);
  u16* hidh    = (u16*)alloc((size_t)T_ * HID_ * 2);
  u16* hidl    = (u16*)alloc((size_t)T_ * HID_ * 2);
  float2* rtab = (float2*)alloc((size_t)T_ * 32 * 8);
  u16* qch     = (u16*)alloc((size_t)T_ * QLR_ * 2);
  u16* qcl     = (u16*)alloc((size_t)T_ * QLR_ * 2);
  u16* wiqh    = (u16*)alloc((size_t)(IDXH_ * IDXD_) * QLR_ * 2);
  u16* wiql    = (u16*)alloc((size_t)(IDXH_ * IDXD_) * QLR_ * 2);
  u16* qih     = qch;
  u16* qil     = qch + (size_t)T_ * IDXH_ * IDXD_;
  float* qi    = (float*)alloc((size_t)T_ * IDXH_ * IDXD_ * 4);
  u16* qeff    = (u16*)qi;
  float* score = (float*)alloc((size_t)T_ * T_ * 4);
  u16* qfb     = (u16*)score;
  u16* attno   = (u16*)score;
  u16* wcath   = (u16*)alloc((size_t)QKVX_ * HID_ * 2);
  u16* wcatl   = (u16*)alloc((size_t)QKVX_ * HID_ * 2);
  float* qkvx  = (float*)alloc((size_t)T_ * QKVX_ * 4);
  u16* Olat    = wcath;
  u16* wqbt    = (u16*)alloc((size_t)(H_ * QKD_) * QLR_ * 2);
  u16* wkvb    = (u16*)alloc((size_t)KVLR_ * (H_ * 256) * 2);
  u16* wkvbt   = (u16*)alloc((size_t)(H_ * 256) * KVLR_ * 2);
  u16* wot     = (u16*)alloc((size_t)(H_ * VD_) * HID_ * 2);

  dim3 blk(256);
  auto g2 = [](int M, int N, int Z) { return dim3((N + 127) / 128, M / 128, Z); };

  rope_tab_kernel<<<(T_ * 32 + 255) / 256, blk, 0, stream>>>(rtab);
  {
    TSJob j0{w_qkv_a, wcath, wcatl, HID_, QKVN_};
    TSJob j1{w_idx_qb, wiqh, wiql, QLR_, IDXH_ * IDXD_};
    TSJob j2{w_idx_k, wcath + (size_t)QKVN_ * HID_, wcatl + (size_t)QKVN_ * HID_, HID_, IDXD_};
    TSJob j3{w_wproj, wcath + (size_t)(QKVN_ + IDXD_) * HID_, wcatl + (size_t)(QKVN_ + IDXD_) * HID_, HID_, IDXH_};
    transpose_split_multi<<<dim3(64, 32, 4), blk, 0, stream>>>(j0, j1, j2, j3);
  }
  {
    TBJob j0{w_qb, wqbt, QLR_, H_ * QKD_};
    TBJob j1{w_kvb, wkvbt, KVLR_, H_ * 256};
    TBJob j2{w_o, wot, H_ * VD_, HID_};
    transpose_bf16_multi<<<dim3(64, 32, 3), blk, 0, stream>>>(j0, j1, j2);
  }
  split_f16_k<<<2048, blk, 0, stream>>>(hidden, hidh, hidl, (long)T_ * HID_);
  conv_bf16_k<<<2048, blk, 0, stream>>>(w_kvb, wkvb, (long)KVLR_ * H_ * 256);

  gemm_hl<<<g2(T_, QKVX_, 1), blk, 0, stream>>>(
      hidh, hidl, HID_, wcath, wcatl, HID_, qkvx, QKVX_,
      b_wproj, QKVN_ + IDXD_, 0.015625f, QKVX_, HID_);
  rmsnorm_kernel<<<T_, blk, 0, stream>>>(qkvx, q_a_ln_w, kv_a_ln_w, qcb, qch, qcl, kv_cn);
  rope_kpe_kernel<<<T_, 64, 0, stream>>>(qkvx, rtab, kper);
  ki_ln_rope_kernel<<<T_, 128, 0, stream>>>(qkvx, idx_g, idx_b, rtab, kih, kil);

  gemm_hl<<<g2(T_, IDXH_ * IDXD_, 1), blk, 0, stream>>>(
      qch, qcl, QLR_, wiqh, wiql, QLR_, qi, IDXH_ * IDXD_,
      nullptr, 1 << 30, 1.f, IDXH_ * IDXD_, QLR_);
  rope_qi_split_kernel<<<T_, blk, 0, stream>>>(qi, rtab, qih, qil);

  score_mfma<<<dim3(32, 32), blk, 0, stream>>>(qih, qil, kih, kil,
                                               qkvx + QKVN_ + IDXD_, QKVX_, score);
  topk_kernel<<<T_, blk, 0, stream>>>(score, selidx, selcnt);

  gemm_t<1><<<g2(T_, H_ * QKD_, 1), blk, 0, stream>>>(qcb, QLR_, 0, wqbt, QLR_, 0, qfb, H_ * QKD_, 0, H_ * QKD_, QLR_);
  rope_q_bf_kernel<<<T_, blk, 0, stream>>>(qfb, rtab);
  gemm_t<1><<<g2(T_, 512, H_), blk, 0, stream>>>(qfb, H_ * QKD_, QKD_, wkvb, H_ * 256, 256, qeff, H_ * 512, 512, 512, NOPE_);
  attn_mla_kernel<<<T_, blk, 0, stream>>>(qeff, qfb, kv_cn, kper, selidx, selcnt, Olat);
  gemm_t<1><<<g2(T_, VD_, H_), blk, 0, stream>>>(Olat, H_ * 512, 512, wkvbt + 128 * 512, KVLR_, 256 * 512, attno, H_ * VD_, VD_, VD_, 512);
  gemm_t<0><<<g2(T_, HID_, 1), blk, 0, stream>>>(attno, H_ * VD_, 0, wot, H_ * VD_, 0, d_out, HID_, 0, HID_, H_ * VD_);
}

// Round 19
// 662.541 us; speedup vs baseline: 1.0427x; 1.0427x over previous
//
#include <hip/hip_runtime.h>
#include <cfloat>
#include <cmath>

#define T_    2048
#define HID_  2048
#define QKVN_ 2112
#define QKVX_ 2272   // fused: 2112 qkv | 128 ki | 32 wgt
#define QLR_  1536
#define KVLR_ 512
#define ROPE_ 64
#define NOPE_ 128
#define QKD_  192
#define VD_   128
#define H_    16
#define IDXH_ 32
#define IDXD_ 128
#define TOPK_ 512
#define EPS_  1e-6f
#define SCALING_ 0.07216878364870323f   // 192^-0.5

typedef unsigned int u32;
typedef unsigned short u16;
typedef __bf16 bf16x8 __attribute__((ext_vector_type(8)));
typedef _Float16 f16;
typedef f16 f16x8 __attribute__((ext_vector_type(8)));
typedef float f32x4 __attribute__((ext_vector_type(4)));

__device__ __forceinline__ u16 f2bf(float x) {
  u32 u = __float_as_uint(x);
  u32 r = (u + 0x7fffu + ((u >> 16) & 1u)) >> 16;
  return (u16)r;
}
__device__ __forceinline__ float bf2f(u16 h) { return __uint_as_float(((u32)h) << 16); }
__device__ __forceinline__ u32 pack2(float a, float b) { return (u32)f2bf(a) | ((u32)f2bf(b) << 16); }
__device__ __forceinline__ bf16x8 ld8(const void* p) { return *(const bf16x8*)p; }
__device__ __forceinline__ f32x4 mfma16(bf16x8 a, bf16x8 b, f32x4 c) {
  return __builtin_amdgcn_mfma_f32_16x16x32_bf16(a, b, c, 0, 0, 0);
}
__device__ __forceinline__ u16 hbits(f16 h) { union { f16 h; u16 u; } c; c.h = h; return c.u; }
__device__ __forceinline__ u32 hpack(f16 a, f16 b) { return (u32)hbits(a) | ((u32)hbits(b) << 16); }
__device__ __forceinline__ f16x8 ldh8(const void* p) { return *(const f16x8*)p; }
__device__ __forceinline__ f32x4 mfmah(f16x8 a, f16x8 b, f32x4 c) {
  return __builtin_amdgcn_mfma_f32_16x16x32_f16(a, b, c, 0, 0, 0);
}
__device__ __forceinline__ void gload16(const u16* g, u16* l) {
  __builtin_amdgcn_global_load_lds(
      (__attribute__((address_space(1))) void*)(g),
      (__attribute__((address_space(3))) void*)(l), 16, 0, 0);
}

// ---------------------------------------------------------------- rope table
__global__ __launch_bounds__(256) void rope_tab_kernel(float2* __restrict__ tab) {
  int i = blockIdx.x * 256 + threadIdx.x;
  if (i >= T_ * 32) return;
  int t = i >> 5, j = i & 31;
  float inv = powf(10000.f, -(float)j * (1.f / 32.f));
  float f = (float)t * inv;
  tab[i] = make_float2(cosf(f), sinf(f));
}
__device__ __forceinline__ void rope_apply(float2 cs, float& x0, float& x1) {
  float a = x0, b = x1;
  x0 = a * cs.x - b * cs.y;
  x1 = a * cs.y + b * cs.x;
}

// ---------------------------------------------------------------- prep (multi-job)
struct TSJob { const float* src; u16* oh; u16* ol; int K; int N; };
__global__ __launch_bounds__(256) void transpose_split_multi(
    TSJob j0, TSJob j1, TSJob j2, TSJob j3) {
  TSJob jb = (blockIdx.z == 0) ? j0 : (blockIdx.z == 1) ? j1 : (blockIdx.z == 2) ? j2 : j3;
  int k0 = blockIdx.y * 64, n0 = blockIdx.x * 64;
  if (k0 >= jb.K || n0 >= jb.N) return;
  __shared__ float t[64][65];
  for (int j = 0; j < 16; ++j) {
    int u = threadIdx.x + 256 * j; int r = u >> 6, c = u & 63;
    t[r][c] = (k0 + r < jb.K && n0 + c < jb.N) ? jb.src[(size_t)(k0 + r) * jb.N + n0 + c] : 0.f;
  }
  __syncthreads();
  for (int j = 0; j < 16; ++j) {
    int u = threadIdx.x + 256 * j; int r = u >> 6, c = u & 63;
    if (n0 + r < jb.N && k0 + c < jb.K) {
      float v = t[c][r];
      f16 h = (f16)v;
      jb.oh[(size_t)(n0 + r) * jb.K + k0 + c] = hbits(h);
      jb.ol[(size_t)(n0 + r) * jb.K + k0 + c] = hbits((f16)(v - (float)h));
    }
  }
}

struct TBJob { const float* src; u16* out; int K; int N; };
__global__ __launch_bounds__(256) void transpose_bf16_multi(TBJob j0, TBJob j1, TBJob j2) {
  TBJob jb = (blockIdx.z == 0) ? j0 : (blockIdx.z == 1) ? j1 : j2;
  int k0 = blockIdx.y * 64, n0 = blockIdx.x * 64;
  if (k0 >= jb.K || n0 >= jb.N) return;
  __shared__ float t[64][65];
  for (int j = 0; j < 16; ++j) {
    int u = threadIdx.x + 256 * j; int r = u >> 6, c = u & 63;
    t[r][c] = (k0 + r < jb.K && n0 + c < jb.N) ? jb.src[(size_t)(k0 + r) * jb.N + n0 + c] : 0.f;
  }
  __syncthreads();
  for (int j = 0; j < 16; ++j) {
    int u = threadIdx.x + 256 * j; int r = u >> 6, c = u & 63;
    if (n0 + r < jb.N && k0 + c < jb.K) jb.out[(size_t)(n0 + r) * jb.K + k0 + c] = f2bf(t[c][r]);
  }
}

__global__ __launch_bounds__(256) void split_f16_k(
    const float* __restrict__ in, u16* __restrict__ hi, u16* __restrict__ lo, long n) {
  for (long i = ((long)blockIdx.x * 256 + threadIdx.x) * 4; i < n; i += (long)gridDim.x * 1024) {
    float4 v = *(const float4*)(in + i);
    f16 a = (f16)v.x, b = (f16)v.y, c = (f16)v.z, d = (f16)v.w;
    *(u32*)(hi + i) = hpack(a, b);
    *(u32*)(hi + i + 2) = hpack(c, d);
    *(u32*)(lo + i) = hpack((f16)(v.x - (float)a), (f16)(v.y - (float)b));
    *(u32*)(lo + i + 2) = hpack((f16)(v.z - (float)c), (f16)(v.w - (float)d));
  }
}

__global__ __launch_bounds__(256) void conv_bf16_k(
    const float* __restrict__ in, u16* __restrict__ out, long n) {
  for (long i = ((long)blockIdx.x * 256 + threadIdx.x) * 4; i < n; i += (long)gridDim.x * 1024) {
    float4 v = *(const float4*)(in + i);
    *(u32*)(out + i) = pack2(v.x, v.y);
    *(u32*)(out + i + 2) = pack2(v.z, v.w);
  }
}

// ---------------------------------------------------------------- strict GEMM (DMA-staged hi/lo)
__global__ __launch_bounds__(256) void gemm_hl(
    const u16* __restrict__ Ah_, const u16* __restrict__ Al_, int lda,
    const u16* __restrict__ Bh_, const u16* __restrict__ Bl_, int ldb,
    float* __restrict__ C, int ldc, const float* __restrict__ bias, int bcol0,
    float bscale, int N, int K) {
  __shared__ u32 Ah[128][16], Al[128][16], Bh[128][16], Bl[128][16];
  const int tid = threadIdx.x;
  const int bm = blockIdx.y * 128, bn = blockIdx.x * 128;
  const int wid = tid >> 6, lane = tid & 63, wr = wid >> 1, wc = wid & 1;
  const int lr = lane & 15, lg = lane >> 4;
  const u16* srcb = (wid == 0) ? Ah_ : (wid == 1) ? Al_ : (wid == 2) ? Bh_ : Bl_;
  const int sld = (wid < 2) ? lda : ldb;
  const int rb = (wid < 2) ? bm : bn;
  u16* dst = (u16*)((wid == 0) ? &Ah[0][0] : (wid == 1) ? &Al[0][0]
                                           : (wid == 2) ? &Bh[0][0] : &Bl[0][0]);
  const int rowl = lane >> 2;
  const int offl = (lane & 3) * 8;
  f32x4 acc[4][4] = {};
  for (int k0 = 0; k0 < K; k0 += 32) {
#pragma unroll
    for (int c = 0; c < 8; ++c) {
      int gr = rb + c * 16 + rowl;
      if (wid >= 2) gr = min(gr, N - 1);
      gload16(srcb + (size_t)gr * sld + k0 + offl, dst + c * 512);
    }
    __syncthreads();
    f16x8 ah[4], al[4], bh[4], bl[4];
#pragma unroll
    for (int i = 0; i < 4; ++i) {
      ah[i] = ldh8(&Ah[wr * 64 + i * 16 + lr][lg * 4]);
      al[i] = ldh8(&Al[wr * 64 + i * 16 + lr][lg * 4]);
      bh[i] = ldh8(&Bh[wc * 64 + i * 16 + lr][lg * 4]);
      bl[i] = ldh8(&Bl[wc * 64 + i * 16 + lr][lg * 4]);
    }
#pragma unroll
    for (int i = 0; i < 4; ++i)
#pragma unroll
      for (int jn = 0; jn < 4; ++jn) {
        acc[i][jn] = mfmah(ah[i], bh[jn], acc[i][jn]);
        acc[i][jn] = mfmah(ah[i], bl[jn], acc[i][jn]);
        acc[i][jn] = mfmah(al[i], bh[jn], acc[i][jn]);
      }
    __syncthreads();
  }
#pragma unroll
  for (int i = 0; i < 4; ++i)
#pragma unroll
    for (int jn = 0; jn < 4; ++jn)
#pragma unroll
      for (int j = 0; j < 4; ++j) {
        int row = bm + wr * 64 + i * 16 + lg * 4 + j;
        int col = bn + wc * 64 + jn * 16 + lr;
        if (col < N) {
          float v = acc[i][jn][j];
          if (col >= bcol0) v = (v + bias[col - bcol0]) * bscale;
          C[(size_t)row * ldc + col] = v;
        }
      }
}

// ---------------------------------------------------------------- tolerant bf16 GEMM (DMA-staged)
template <int CBF16>
__global__ __launch_bounds__(256) void gemm_t(
    const u16* __restrict__ Ab, int lda, long aoz,
    const u16* __restrict__ Bt, int ldb, long boz,
    void* __restrict__ Cp, int ldc, long coz, int N, int K) {
  __shared__ u32 As[128][16], Bs[128][16];
  const int tid = threadIdx.x;
  const int z = blockIdx.z;
  const int bm = blockIdx.y * 128, bn = blockIdx.x * 128;
  const int wid = tid >> 6, lane = tid & 63, wr = wid >> 1, wc = wid & 1;
  const int lr = lane & 15, lg = lane >> 4;
  const u16* A = Ab + aoz * z;
  const u16* B = Bt + boz * z;
  const u16* srcb = (wid < 2) ? A : B;
  const int sld = (wid < 2) ? lda : ldb;
  const int rb = (wid < 2) ? bm : bn;
  u16* dst = (u16*)((wid < 2) ? &As[0][0] : &Bs[0][0]);
  const int ccb = (wid & 1) * 4;
  const int rowl = lane >> 2;
  const int offl = (lane & 3) * 8;
  f32x4 acc[4][4] = {};
  for (int k0 = 0; k0 < K; k0 += 32) {
#pragma unroll
    for (int c = 0; c < 4; ++c) {
      int cc = ccb + c;
      int gr = rb + cc * 16 + rowl;
      if (wid >= 2) gr = min(gr, N - 1);
      gload16(srcb + (size_t)gr * sld + k0 + offl, dst + cc * 512);
    }
    __syncthreads();
    bf16x8 af[4], bf[4];
#pragma unroll
    for (int i = 0; i < 4; ++i) {
      af[i] = ld8(&As[wr * 64 + i * 16 + lr][lg * 4]);
      bf[i] = ld8(&Bs[wc * 64 + i * 16 + lr][lg * 4]);
    }
#pragma unroll
    for (int i = 0; i < 4; ++i)
#pragma unroll
      for (int jn = 0; jn < 4; ++jn)
        acc[i][jn] = mfma16(af[i], bf[jn], acc[i][jn]);
    __syncthreads();
  }
#pragma unroll
  for (int i = 0; i < 4; ++i)
#pragma unroll
    for (int jn = 0; jn < 4; ++jn)
#pragma unroll
      for (int j = 0; j < 4; ++j) {
        int row = bm + wr * 64 + i * 16 + lg * 4 + j;
        int col = bn + wc * 64 + jn * 16 + lr;
        if (col < N) {
          if (CBF16) ((u16*)Cp)[coz * z + (size_t)row * ldc + col] = f2bf(acc[i][jn][j]);
          else ((float*)Cp)[coz * z + (size_t)row * ldc + col] = acc[i][jn][j];
        }
      }
}

// ---------------------------------------------------------------- RMS norms (q_cn -> f16 hi/lo + bf16)
__global__ __launch_bounds__(256) void rmsnorm_kernel(
    const float* __restrict__ qkvx, const float* __restrict__ qw,
    const float* __restrict__ kvw, u16* __restrict__ qcb,
    u16* __restrict__ qch, u16* __restrict__ qcl, u16* __restrict__ kv_cn) {
  const int t = blockIdx.x, tid = threadIdx.x;
  const float* row = qkvx + (size_t)t * QKVX_;
  __shared__ float red[256];
  float ss = 0.f;
  for (int i = tid; i < QLR_; i += 256) { float v = row[i]; ss += v * v; }
  red[tid] = ss; __syncthreads();
  for (int s = 128; s; s >>= 1) { if (tid < s) red[tid] += red[tid + s]; __syncthreads(); }
  float scl = 1.0f / sqrtf(red[0] / (float)QLR_ + EPS_);
  for (int i = tid; i < QLR_; i += 256) {
    float val = row[i] * scl * qw[i];
    qcb[(size_t)t * QLR_ + i] = f2bf(val);
    f16 h = (f16)val;
    qch[(size_t)t * QLR_ + i] = hbits(h);
    qcl[(size_t)t * QLR_ + i] = hbits((f16)(val - (float)h));
  }
  __syncthreads();
  ss = 0.f;
  for (int i = tid; i < KVLR_; i += 256) { float v = row[QLR_ + i]; ss += v * v; }
  red[tid] = ss; __syncthreads();
  for (int s = 128; s; s >>= 1) { if (tid < s) red[tid] += red[tid + s]; __syncthreads(); }
  scl = 1.0f / sqrtf(red[0] / (float)KVLR_ + EPS_);
  for (int i = tid; i < KVLR_; i += 256)
    kv_cn[(size_t)t * KVLR_ + i] = f2bf(row[QLR_ + i] * scl * kvw[i]);
}

// ---------------------------------------------------------------- rope users (table-driven)
__global__ __launch_bounds__(256) void rope_qi_split_kernel(
    const float* __restrict__ qi, const float2* __restrict__ tab,
    u16* __restrict__ qih, u16* __restrict__ qil) {
  const int t = blockIdx.x, tid = threadIdx.x;
  const float* src = qi + (size_t)t * (IDXH_ * IDXD_);
  u16* dh = qih + (size_t)t * (IDXH_ * IDXD_);
  u16* dl = qil + (size_t)t * (IDXH_ * IDXD_);
  for (int p = tid; p < IDXH_ * IDXD_ / 2; p += 256) {
    int d = p & 63;
    float x0 = src[2 * p], x1 = src[2 * p + 1];
    if (d < 32) rope_apply(tab[t * 32 + d], x0, x1);
    f16 h0 = (f16)x0, h1 = (f16)x1;
    *(u32*)(dh + 2 * p) = hpack(h0, h1);
    *(u32*)(dl + 2 * p) = hpack((f16)(x0 - (float)h0), (f16)(x1 - (float)h1));
  }
}

__global__ __launch_bounds__(256) void rope_q_bf_kernel(
    u16* __restrict__ qfb, const float2* __restrict__ tab) {
  const int t = blockIdx.x, tid = threadIdx.x;
  for (int idx = tid; idx < H_ * 32; idx += 256) {
    int hh = idx / 32, j = idx % 32;
    u16* p = qfb + (size_t)t * (H_ * QKD_) + hh * QKD_ + NOPE_ + 2 * j;
    float x0 = bf2f(p[0]), x1 = bf2f(p[1]);
    rope_apply(tab[t * 32 + j], x0, x1);
    p[0] = f2bf(x0); p[1] = f2bf(x1);
  }
}

__global__ __launch_bounds__(64) void rope_kpe_kernel(
    const float* __restrict__ qkvx, const float2* __restrict__ tab,
    u16* __restrict__ kper) {
  const int t = blockIdx.x, tid = threadIdx.x;
  if (tid >= 32) return;
  const float* p = qkvx + (size_t)t * QKVX_ + (QLR_ + KVLR_);
  float x0 = p[2 * tid], x1 = p[2 * tid + 1];
  rope_apply(tab[t * 32 + tid], x0, x1);
  kper[(size_t)t * ROPE_ + 2 * tid] = f2bf(x0);
  kper[(size_t)t * ROPE_ + 2 * tid + 1] = f2bf(x1);
}

__global__ __launch_bounds__(128) void ki_ln_rope_kernel(
    const float* __restrict__ qkvx, const float* __restrict__ gamma,
    const float* __restrict__ beta, const float2* __restrict__ tab,
    u16* __restrict__ kih, u16* __restrict__ kil) {
  const int t = blockIdx.x, tid = threadIdx.x;
  __shared__ float x[128];
  __shared__ float red[128];
  float v = qkvx[(size_t)t * QKVX_ + QKVN_ + tid];
  red[tid] = v; __syncthreads();
  for (int s = 64; s; s >>= 1) { if (tid < s) red[tid] += red[tid + s]; __syncthreads(); }
  float mu = red[0] / 128.f;
  __syncthreads();
  float d = v - mu;
  red[tid] = d * d; __syncthreads();
  for (int s = 64; s; s >>= 1) { if (tid < s) red[tid] += red[tid + s]; __syncthreads(); }
  float var = red[0] / 128.f;
  float y = d * (1.0f / sqrtf(var + EPS_)) * gamma[tid] + beta[tid];
  x[tid] = y; __syncthreads();
  if (tid < 32) {
    float x0 = x[2 * tid], x1 = x[2 * tid + 1];
    rope_apply(tab[t * 32 + tid], x0, x1);
    x[2 * tid] = x0; x[2 * tid + 1] = x1;
  }
  __syncthreads();
  float fv = x[tid];
  f16 h = (f16)fv;
  kih[(size_t)t * IDXD_ + tid] = hbits(h);
  kil[(size_t)t * IDXD_ + tid] = hbits((f16)(fv - (float)h));
}

// ---------------------------------------------------------------- indexer score (pre-split f16 MFMA)
__global__ __launch_bounds__(256) void score_mfma(
    const u16* __restrict__ qih, const u16* __restrict__ qil,
    const u16* __restrict__ kih, const u16* __restrict__ kil,
    const float* __restrict__ wgt, int ldw, float* __restrict__ score) {
  const int s0 = blockIdx.x * 64, t0 = blockIdx.y * 64;
  if (s0 > t0 + 63) return;
  __shared__ u32 Kh[64][68], Kl[64][68], Qh[64][68], Ql[64][68];
  __shared__ float wts[64][33];
  const int tid = threadIdx.x;
  const int wid = tid >> 6, lane = tid & 63, wr = wid >> 1, wc = wid & 1;
  const int lr = lane & 15, lg = lane >> 4;
#pragma unroll
  for (int j = 0; j < 4; ++j) {
    int u = tid + 256 * j; int row = u >> 4, p = u & 15;
    *(uint4*)&Kh[row][p * 4] = *(const uint4*)(kih + (size_t)(s0 + row) * IDXD_ + p * 8);
    *(uint4*)&Kl[row][p * 4] = *(const uint4*)(kil + (size_t)(s0 + row) * IDXD_ + p * 8);
  }
#pragma unroll
  for (int j = 0; j < 8; ++j) {
    int u = tid + 256 * j; int r = u >> 5, c = u & 31;
    wts[r][c] = wgt[(size_t)(t0 + r) * ldw + c];
  }
  __syncthreads();
  f16x8 bh[2][4], bl[2][4];
#pragma unroll
  for (int ni = 0; ni < 2; ++ni)
#pragma unroll
    for (int kb = 0; kb < 4; ++kb) {
      bh[ni][kb] = ldh8(&Kh[wc * 32 + ni * 16 + lr][kb * 16 + lg * 4]);
      bl[ni][kb] = ldh8(&Kl[wc * 32 + ni * 16 + lr][kb * 16 + lg * 4]);
    }
  f32x4 fin[2][2] = {};
  for (int h = 0; h < IDXH_; ++h) {
#pragma unroll
    for (int j = 0; j < 4; ++j) {
      int u = tid + 256 * j; int row = u >> 4, p = u & 15;
      size_t g = (size_t)(t0 + row) * (IDXH_ * IDXD_) + h * IDXD_ + p * 8;
      *(uint4*)&Qh[row][p * 4] = *(const uint4*)(qih + g);
      *(uint4*)&Ql[row][p * 4] = *(const uint4*)(qil + g);
    }
    __syncthreads();
    f32x4 acch[2][2] = {};
#pragma unroll
    for (int kb = 0; kb < 4; ++kb) {
      f16x8 ah0 = ldh8(&Qh[wr * 32 + lr][kb * 16 + lg * 4]);
      f16x8 ah1 = ldh8(&Qh[wr * 32 + 16 + lr][kb * 16 + lg * 4]);
      f16x8 al0 = ldh8(&Ql[wr * 32 + lr][kb * 16 + lg * 4]);
      f16x8 al1 = ldh8(&Ql[wr * 32 + 16 + lr][kb * 16 + lg * 4]);
#pragma unroll
      for (int ni = 0; ni < 2; ++ni) {
        acch[0][ni] = mfmah(ah0, bh[ni][kb], acch[0][ni]);
        acch[0][ni] = mfmah(ah0, bl[ni][kb], acch[0][ni]);
        acch[0][ni] = mfmah(al0, bh[ni][kb], acch[0][ni]);
        acch[1][ni] = mfmah(ah1, bh[ni][kb], acch[1][ni]);
        acch[1][ni] = mfmah(ah1, bl[ni][kb], acch[1][ni]);
        acch[1][ni] = mfmah(al1, bh[ni][kb], acch[1][ni]);
      }
    }
#pragma unroll
    for (int mi = 0; mi < 2; ++mi)
#pragma unroll
      for (int j = 0; j < 4; ++j) {
        float w = wts[wr * 32 + mi * 16 + lg * 4 + j][h];
        fin[mi][0][j] += w * fmaxf(acch[mi][0][j], 0.f);
        fin[mi][1][j] += w * fmaxf(acch[mi][1][j], 0.f);
      }
    __syncthreads();
  }
#pragma unroll
  for (int mi = 0; mi < 2; ++mi)
#pragma unroll
    for (int ni = 0; ni < 2; ++ni)
#pragma unroll
      for (int j = 0; j < 4; ++j) {
        int row = t0 + wr * 32 + mi * 16 + lg * 4 + j;
        int col = s0 + wc * 32 + ni * 16 + lr;
        score[(size_t)row * T_ + col] = fin[mi][ni][j];
      }
}

// ---------------------------------------------------------------- top-k (exact, 4-bit radix)
__global__ __launch_bounds__(256) void topk_kernel(
    const float* __restrict__ score, int* __restrict__ selidx,
    int* __restrict__ selcnt) {
  const int t = blockIdx.x;
  const int L = t + 1;
  const int tid = threadIdx.x;
  if (L <= TOPK_) {
    for (int j = tid; j < TOPK_; j += 256)
      selidx[(size_t)t * TOPK_ + j] = (j < L) ? j : 0;
    if (tid == 0) selcnt[t] = L;
    return;
  }
  __shared__ unsigned u[T_];
  __shared__ unsigned hist[16];
  __shared__ unsigned sprefix;
  __shared__ int sk;
  __shared__ int part[256];
  for (int i = tid; i < T_; i += 256) {
    float v = (i < L) ? score[(size_t)t * T_ + i] : -FLT_MAX;
    unsigned b = __float_as_uint(v);
    u[i] = (b & 0x80000000u) ? ~b : (b | 0x80000000u);
  }
  if (tid == 0) { sprefix = 0u; sk = TOPK_; }
  __syncthreads();
  for (int pass = 0; pass < 8; ++pass) {
    const int shift = 28 - 4 * pass;
    if (tid < 16) hist[tid] = 0u;
    __syncthreads();
    unsigned pfx = sprefix;
    for (int i = tid; i < L; i += 256) {
      unsigned val = u[i];
      bool match = (pass == 0) || ((val >> (shift + 4)) == pfx);
      if (match) atomicAdd(&hist[(val >> shift) & 15u], 1u);
    }
    __syncthreads();
    if (tid == 0) {
      int k = sk; unsigned cum = 0u; int bsel = 0;
      for (int bb = 15; bb >= 0; --bb) {
        if (cum + hist[bb] >= (unsigned)k) { bsel = bb; sk = k - (int)cum; break; }
        cum += hist[bb];
      }
      sprefix = (sprefix << 4) | (unsigned)bsel;
    }
    __syncthreads();
  }
  const unsigned thr = sprefix;
  const int kEq = sk;
  const int base = tid * 8;
  int eqloc[8]; int esum = 0;
  for (int r = 0; r < 8; ++r) {
    int i = base + r;
    int f = (i < L && u[i] == thr) ? 1 : 0;
    eqloc[r] = esum; esum += f;
  }
  part[tid] = esum; __syncthreads();
  for (int off = 1; off < 256; off <<= 1) {
    int v = (tid >= off) ? part[tid - off] : 0;
    __syncthreads();
    part[tid] += v;
    __syncthreads();
  }
  const int ebase = (tid > 0) ? part[tid - 1] : 0;
  __syncthreads();
  int sloc[8], selflag[8]; int ssum = 0;
  for (int r = 0; r < 8; ++r) {
    int i = base + r;
    int f = 0;
    if (i < L) {
      unsigned ui = u[i];
      if (ui > thr) f = 1;
      else if (ui == thr && (ebase + eqloc[r]) < kEq) f = 1;
    }
    selflag[r] = f; sloc[r] = ssum; ssum += f;
  }
  part[tid] = ssum; __syncthreads();
  for (int off = 1; off < 256; off <<= 1) {
    int v = (tid >= off) ? part[tid - off] : 0;
    __syncthreads();
    part[tid] += v;
    __syncthreads();
  }
  const int sbase = (tid > 0) ? part[tid - 1] : 0;
  for (int r = 0; r < 8; ++r)
    if (selflag[r]) selidx[(size_t)t * TOPK_ + sbase + sloc[r]] = base + r;
  if (tid == 0) selcnt[t] = TOPK_;
}

// ---------------------------------------------------------------- MLA attention v8
// QK: 2-deep pipelined per-wave DMA staging (counted vmcnt(4)), swizzled.
// PV: pair-packed LDS with stride-132 rows (write conflicts eliminated).
__global__ __launch_bounds__(256, 3) void attn_mla_kernel(
    const u16* __restrict__ qeff, const u16* __restrict__ qfb,
    const u16* __restrict__ kvcn, const u16* __restrict__ kper,
    const int* __restrict__ selidx, const int* __restrict__ selcnt,
    u16* __restrict__ Olat) {
  const int t = blockIdx.x;
  const int tid = threadIdx.x;
  const int wid = tid >> 6, lane = tid & 63;
  const int lr = lane & 15, lg = lane >> 4;
  __shared__ int sidxs[512];
  __shared__ u16 Pb[16][520];
  __shared__ __align__(16) u16 SB[4][4224];  // QK: 2 x 2048-u16 bufs; PV: u32[16][132]
  __shared__ float redm[4][16];
  __shared__ float reds[4][16];
  const int cnt = selcnt[t];
  for (int j = tid; j < 512; j += 256) sidxs[j] = selidx[(size_t)t * TOPK_ + j];
  __syncthreads();

  const int kl = lane >> 2;
  const int pcs = (((lane & 3) ^ ((lane >> 3) & 3))) << 3;
  const int rsw = ((lr >> 1) & 3) << 3;
  int skey[8];
#pragma unroll
  for (int j = 0; j < 8; ++j) skey[j] = sidxs[wid * 128 + j * 16 + kl];
  u16* buf0 = &SB[wid][0];
  u16* buf1 = &SB[wid][2048];

  const u16* qe = qeff + (size_t)t * (H_ * 512) + lr * 512 + lg * 8;
  const u16* qp = qfb + (size_t)t * (H_ * QKD_) + lr * QKD_ + NOPE_ + lg * 8;
  bf16x8 qf[18];
#pragma unroll
  for (int kb = 0; kb < 16; ++kb) qf[kb] = ld8(qe + kb * 32);
  qf[16] = ld8(qp);
  qf[17] = ld8(qp + 32);

  f32x4 lgv[8] = {};
#pragma unroll
  for (int j = 0; j < 4; ++j)
    gload16(kvcn + (size_t)skey[j] * 512 + pcs, buf0 + j * 512);
#pragma unroll
  for (int j = 0; j < 4; ++j)
    gload16(kvcn + (size_t)skey[4 + j] * 512 + pcs, buf1 + j * 512);
#pragma unroll
  for (int s = 0; s < 36; ++s) {
    const int kb = s >> 1, h = s & 1;
    u16* b = (h == 0) ? buf0 : buf1;
    if (s == 35) { asm volatile("s_waitcnt vmcnt(0)" ::: "memory"); }
    else         { asm volatile("s_waitcnt vmcnt(4)" ::: "memory"); }
    __builtin_amdgcn_sched_barrier(0);
    bf16x8 kf[4];
#pragma unroll
    for (int i = 0; i < 4; ++i)
      kf[i] = ld8(b + (i * 16 + lr) * 32 + (lg * 8 ^ rsw));
#pragma unroll
    for (int i = 0; i < 4; ++i)
      lgv[h * 4 + i] = mfma16(kf[i], qf[kb], lgv[h * 4 + i]);
    asm volatile("s_waitcnt lgkmcnt(0)" ::: "memory");
    __builtin_amdgcn_sched_barrier(0);
    if (s + 2 < 36) {
      const int kb2 = (s + 2) >> 1;
      if (kb2 < 16) {
#pragma unroll
        for (int j = 0; j < 4; ++j)
          gload16(kvcn + (size_t)skey[h * 4 + j] * 512 + kb2 * 32 + pcs, b + j * 512);
      } else {
#pragma unroll
        for (int j = 0; j < 4; ++j)
          gload16(kper + (size_t)skey[h * 4 + j] * 64 + (kb2 - 16) * 32 + pcs, b + j * 512);
      }
    }
  }

  float mx = -FLT_MAX;
#pragma unroll
  for (int m = 0; m < 8; ++m)
#pragma unroll
    for (int j = 0; j < 4; ++j) {
      int slot = wid * 128 + m * 16 + lg * 4 + j;
      float v = (slot < cnt) ? lgv[m][j] * SCALING_ : -FLT_MAX;
      lgv[m][j] = v;
      mx = fmaxf(mx, v);
    }
  mx = fmaxf(mx, __shfl_xor(mx, 16));
  mx = fmaxf(mx, __shfl_xor(mx, 32));
  if (lane < 16) redm[wid][lane] = mx;
  __syncthreads();
  float hm = fmaxf(fmaxf(redm[0][lr], redm[1][lr]), fmaxf(redm[2][lr], redm[3][lr]));
  float sm = 0.f;
#pragma unroll
  for (int m = 0; m < 8; ++m)
#pragma unroll
    for (int j = 0; j < 4; ++j) {
      int slot = wid * 128 + m * 16 + lg * 4 + j;
      float e = (slot < cnt) ? expf(lgv[m][j] - hm) : 0.f;
      lgv[m][j] = e; sm += e;
    }
  sm += __shfl_xor(sm, 16);
  sm += __shfl_xor(sm, 32);
  if (lane < 16) reds[wid][lane] = sm;
  __syncthreads();
  float inv = 1.f / (reds[0][lr] + reds[1][lr] + reds[2][lr] + reds[3][lr]);
#pragma unroll
  for (int m = 0; m < 8; ++m) {
    int sl = wid * 128 + m * 16 + lg * 4;
    *(u32*)&Pb[lr][sl] = pack2(lgv[m][0] * inv, lgv[m][1] * inv);
    *(u32*)&Pb[lr][sl + 2] = pack2(lgv[m][2] * inv, lgv[m][3] * inv);
  }
  __syncthreads();

  u32* vpw = (u32*)&SB[wid][0];
  const int pl = lane >> 4;
  const int gq = lane & 15;
  const u16* vsrc = kvcn + wid * 128 + gq * 8;
  f32x4 oacc[8] = {};
  uint4 ra[4], rb[4];
#pragma unroll
  for (int s = 0; s < 4; ++s) {
    int p = s * 4 + pl;
    ra[s] = *(const uint4*)(vsrc + (size_t)sidxs[2 * p] * 512);
    rb[s] = *(const uint4*)(vsrc + (size_t)sidxs[2 * p + 1] * 512);
  }
  for (int c = 0; c < 16; ++c) {
#pragma unroll
    for (int s = 0; s < 4; ++s) {
      int p = s * 4 + pl;
      int col = (gq * 8) ^ ((s & 3) << 3);
      const u16* A = (const u16*)&ra[s];
      const u16* B = (const u16*)&rb[s];
      u32 w[8];
#pragma unroll
      for (int j = 0; j < 8; ++j) w[j] = (u32)A[j] | ((u32)B[j] << 16);
      *(uint4*)&vpw[p * 132 + col] = make_uint4(w[0], w[1], w[2], w[3]);
      *(uint4*)&vpw[p * 132 + col + 4] = make_uint4(w[4], w[5], w[6], w[7]);
    }
    if (c < 15) {
#pragma unroll
      for (int s = 0; s < 4; ++s) {
        int p = s * 4 + pl;
        ra[s] = *(const uint4*)(vsrc + (size_t)sidxs[(c + 1) * 32 + 2 * p] * 512);
        rb[s] = *(const uint4*)(vsrc + (size_t)sidxs[(c + 1) * 32 + 2 * p + 1] * 512);
      }
    }
    bf16x8 pa = ld8(&Pb[lr][c * 32 + lg * 8]);
    union BB { u32 u[4]; bf16x8 v; };
    BB bb[8];
#pragma unroll
    for (int C = 0; C < 8; ++C) {
      int col = (C * 16 + lr) ^ (lg << 3);
#pragma unroll
      for (int e = 0; e < 4; ++e)
        bb[C].u[e] = vpw[(lg * 4 + e) * 132 + col];
    }
    __builtin_amdgcn_s_setprio(1);
#pragma unroll
    for (int C = 0; C < 8; ++C) oacc[C] = mfma16(pa, bb[C].v, oacc[C]);
    __builtin_amdgcn_s_setprio(0);
  }
#pragma unroll
  for (int C = 0; C < 8; ++C)
#pragma unroll
    for (int j = 0; j < 4; ++j) {
      int h = lg * 4 + j;
      Olat[(size_t)t * (H_ * 512) + h * 512 + wid * 128 + C * 16 + lr] = f2bf(oacc[C][j]);
    }
}

// ---------------------------------------------------------------- launch
extern "C" void kernel_launch(void* const* d_in, const int* in_sizes, int n_in,
                              void* d_out, int out_size, void* d_ws, size_t ws_size,
                              hipStream_t stream) {
  const float* hidden    = (const float*)d_in[1];
  const float* w_qkv_a   = (const float*)d_in[2];
  const float* q_a_ln_w  = (const float*)d_in[3];
  const float* w_qb      = (const float*)d_in[4];
  const float* kv_a_ln_w = (const float*)d_in[5];
  const float* w_kvb     = (const float*)d_in[6];
  const float* w_o       = (const float*)d_in[7];
  const float* w_idx_qb  = (const float*)d_in[8];
  const float* w_idx_k   = (const float*)d_in[9];
  const float* idx_g     = (const float*)d_in[10];
  const float* idx_b     = (const float*)d_in[11];
  const float* w_wproj   = (const float*)d_in[12];
  const float* b_wproj   = (const float*)d_in[13];

  char* W = (char*)d_ws;
  size_t o = 0;
  auto alloc = [&](size_t bytes) { void* p = W + o; o += (bytes + 255) & ~(size_t)255; return p; };
  u16* qcb     = (u16*)alloc((size_t)T_ * QLR_ * 2);
  u16* kv_cn   = (u16*)alloc((size_t)T_ * KVLR_ * 2);
  u16* kper    = (u16*)alloc((size_t)T_ * ROPE_ * 2);
  int* selidx  = (int*)alloc((size_t)T_ * TOPK_ * 4);
  int* selcnt  = (int*)alloc((size_t)T_ * 4);
  u16* kih     = (u16*)alloc((size_t)T_ * IDXD_ * 2);
  u16* kil     = (u16*)alloc((size_t)T_ * IDXD_ * 2);
  u16* hidh    = (u16*)alloc((size_t)T_ * HID_ * 2);
  u16* hidl    = (u16*)alloc((size_t)T_ * HID_ * 2);
  float2* rtab = (float2*)alloc((size_t)T_ * 32 * 8);
  u16* qch     = (u16*)alloc((size_t)T_ * QLR_ * 2);
  u16* qcl     = (u16*)alloc((size_t)T_ * QLR_ * 2);
  u16* wiqh    = (u16*)alloc((size_t)(IDXH_ * IDXD_) * QLR_ * 2);
  u16* wiql    = (u16*)alloc((size_t)(IDXH_ * IDXD_) * QLR_ * 2);
  u16* qih     = qch;
  u16* qil     = qch + (size_t)T_ * IDXH_ * IDXD_;
  float* qi    = (float*)alloc((size_t)T_ * IDXH_ * IDXD_ * 4);
  u16* qeff    = (u16*)qi;
  float* score = (float*)alloc((size_t)T_ * T_ * 4);
  u16* qfb     = (u16*)score;
  u16* attno   = (u16*)score;
  u16* wcath   = (u16*)alloc((size_t)QKVX_ * HID_ * 2);
  u16* wcatl   = (u16*)alloc((size_t)QKVX_ * HID_ * 2);
  float* qkvx  = (float*)alloc((size_t)T_ * QKVX_ * 4);
  u16* Olat    = wcath;
  u16* wqbt    = (u16*)alloc((size_t)(H_ * QKD_) * QLR_ * 2);
  u16* wkvb    = (u16*)alloc((size_t)KVLR_ * (H_ * 256) * 2);
  u16* wkvbt   = (u16*)alloc((size_t)(H_ * 256) * KVLR_ * 2);
  u16* wot     = (u16*)alloc((size_t)(H_ * VD_) * HID_ * 2);

  dim3 blk(256);
  auto g2 = [](int M, int N, int Z) { return dim3((N + 127) / 128, M / 128, Z); };

  rope_tab_kernel<<<(T_ * 32 + 255) / 256, blk, 0, stream>>>(rtab);
  {
    TSJob j0{w_qkv_a, wcath, wcatl, HID_, QKVN_};
    TSJob j1{w_idx_qb, wiqh, wiql, QLR_, IDXH_ * IDXD_};
    TSJob j2{w_idx_k, wcath + (size_t)QKVN_ * HID_, wcatl + (size_t)QKVN_ * HID_, HID_, IDXD_};
    TSJob j3{w_wproj, wcath + (size_t)(QKVN_ + IDXD_) * HID_, wcatl + (size_t)(QKVN_ + IDXD_) * HID_, HID_, IDXH_};
    transpose_split_multi<<<dim3(64, 32, 4), blk, 0, stream>>>(j0, j1, j2, j3);
  }
  {
    TBJob j0{w_qb, wqbt, QLR_, H_ * QKD_};
    TBJob j1{w_kvb, wkvbt, KVLR_, H_ * 256};
    TBJob j2{w_o, wot, H_ * VD_, HID_};
    transpose_bf16_multi<<<dim3(64, 32, 3), blk, 0, stream>>>(j0, j1, j2);
  }
  split_f16_k<<<2048, blk, 0, stream>>>(hidden, hidh, hidl, (long)T_ * HID_);
  conv_bf16_k<<<2048, blk, 0, stream>>>(w_kvb, wkvb, (long)KVLR_ * H_ * 256);

  gemm_hl<<<g2(T_, QKVX_, 1), blk, 0, stream>>>(
      hidh, hidl, HID_, wcath, wcatl, HID_, qkvx, QKVX_,
      b_wproj, QKVN_ + IDXD_, 0.015625f, QKVX_, HID_);
  rmsnorm_kernel<<<T_, blk, 0, stream>>>(qkvx, q_a_ln_w, kv_a_ln_w, qcb, qch, qcl, kv_cn);
  rope_kpe_kernel<<<T_, 64, 0, stream>>>(qkvx, rtab, kper);
  ki_ln_rope_kernel<<<T_, 128, 0, stream>>>(qkvx, idx_g, idx_b, rtab, kih, kil);

  gemm_hl<<<g2(T_, IDXH_ * IDXD_, 1), blk, 0, stream>>>(
      qch, qcl, QLR_, wiqh, wiql, QLR_, qi, IDXH_ * IDXD_,
      nullptr, 1 << 30, 1.f, IDXH_ * IDXD_, QLR_);
  rope_qi_split_kernel<<<T_, blk, 0, stream>>>(qi, rtab, qih, qil);

  score_mfma<<<dim3(32, 32), blk, 0, stream>>>(qih, qil, kih, kil,
                                               qkvx + QKVN_ + IDXD_, QKVX_, score);
  topk_kernel<<<T_, blk, 0, stream>>>(score, selidx, selcnt);

  gemm_t<1><<<g2(T_, H_ * QKD_, 1), blk, 0, stream>>>(qcb, QLR_, 0, wqbt, QLR_, 0, qfb, H_ * QKD_, 0, H_ * QKD_, QLR_);
  rope_q_bf_kernel<<<T_, blk, 0, stream>>>(qfb, rtab);
  gemm_t<1><<<g2(T_, 512, H_), blk, 0, stream>>>(qfb, H_ * QKD_, QKD_, wkvb, H_ * 256, 256, qeff, H_ * 512, 512, 512, NOPE_);
  attn_mla_kernel<<<T_, blk, 0, stream>>>(qeff, qfb, kv_cn, kper, selidx, selcnt, Olat);
  gemm_t<1><<<g2(T_, VD_, H_), blk, 0, stream>>>(Olat, H_ * 512, 512, wkvbt + 128 * 512, KVLR_, 256 * 512, attno, H_ * VD_, VD_, VD_, 512);
  gemm_t<0><<<g2(T_, HID_, 1), blk, 0, stream>>>(attno, H_ * VD_, 0, wot, H_ * VD_, 0, d_out, HID_, 0, HID_, H_ * VD_);
}

// Round 20
// 650.166 us; speedup vs baseline: 1.0626x; 1.0190x over previous
//
#include <hip/hip_runtime.h>
#include <cfloat>
#include <cmath>

#define T_    2048
#define HID_  2048
#define QKVN_ 2112
#define QKVX_ 2272   // fused: 2112 qkv | 128 ki | 32 wgt
#define QLR_  1536
#define KVLR_ 512
#define ROPE_ 64
#define NOPE_ 128
#define QKD_  192
#define VD_   128
#define H_    16
#define IDXH_ 32
#define IDXD_ 128
#define TOPK_ 512
#define EPS_  1e-6f
#define SCALING_ 0.07216878364870323f   // 192^-0.5

typedef unsigned int u32;
typedef unsigned short u16;
typedef __bf16 bf16x8 __attribute__((ext_vector_type(8)));
typedef _Float16 f16;
typedef f16 f16x8 __attribute__((ext_vector_type(8)));
typedef float f32x4 __attribute__((ext_vector_type(4)));

__device__ __forceinline__ u16 f2bf(float x) {
  u32 u = __float_as_uint(x);
  u32 r = (u + 0x7fffu + ((u >> 16) & 1u)) >> 16;
  return (u16)r;
}
__device__ __forceinline__ float bf2f(u16 h) { return __uint_as_float(((u32)h) << 16); }
__device__ __forceinline__ u32 pack2(float a, float b) { return (u32)f2bf(a) | ((u32)f2bf(b) << 16); }
__device__ __forceinline__ bf16x8 ld8(const void* p) { return *(const bf16x8*)p; }
__device__ __forceinline__ f32x4 mfma16(bf16x8 a, bf16x8 b, f32x4 c) {
  return __builtin_amdgcn_mfma_f32_16x16x32_bf16(a, b, c, 0, 0, 0);
}
__device__ __forceinline__ u16 hbits(f16 h) { union { f16 h; u16 u; } c; c.h = h; return c.u; }
__device__ __forceinline__ u32 hpack(f16 a, f16 b) { return (u32)hbits(a) | ((u32)hbits(b) << 16); }
__device__ __forceinline__ f16x8 ldh8(const void* p) { return *(const f16x8*)p; }
__device__ __forceinline__ f32x4 mfmah(f16x8 a, f16x8 b, f32x4 c) {
  return __builtin_amdgcn_mfma_f32_16x16x32_f16(a, b, c, 0, 0, 0);
}
__device__ __forceinline__ void gload16(const u16* g, u16* l) {
  __builtin_amdgcn_global_load_lds(
      (__attribute__((address_space(1))) void*)(g),
      (__attribute__((address_space(3))) void*)(l), 16, 0, 0);
}

__device__ __forceinline__ void rope_apply(float2 cs, float& x0, float& x1) {
  float a = x0, b = x1;
  x0 = a * cs.x - b * cs.y;
  x1 = a * cs.y + b * cs.x;
}

// ---------------------------------------------------------------- prep elementwise (multi-job)
// z=0: rope table; z=1: split hidden f32->f16 hi/lo; z=2: conv wkvb f32->bf16
__global__ __launch_bounds__(256) void prep_elem_multi(
    float2* __restrict__ tab,
    const float* __restrict__ hid, u16* __restrict__ hih, u16* __restrict__ hil,
    const float* __restrict__ wkv, u16* __restrict__ wkvb) {
  const long gid = (long)blockIdx.x * 256 + threadIdx.x;
  const long gstep = (long)gridDim.x * 256;
  if (blockIdx.z == 0) {
    for (long i = gid; i < (long)T_ * 32; i += gstep) {
      int t = (int)(i >> 5), j = (int)(i & 31);
      float inv = powf(10000.f, -(float)j * (1.f / 32.f));
      float f = (float)t * inv;
      tab[i] = make_float2(cosf(f), sinf(f));
    }
  } else if (blockIdx.z == 1) {
    const long n = (long)T_ * HID_;
    for (long i = gid * 4; i < n; i += gstep * 4) {
      float4 v = *(const float4*)(hid + i);
      f16 a = (f16)v.x, b = (f16)v.y, c = (f16)v.z, d = (f16)v.w;
      *(u32*)(hih + i) = hpack(a, b);
      *(u32*)(hih + i + 2) = hpack(c, d);
      *(u32*)(hil + i) = hpack((f16)(v.x - (float)a), (f16)(v.y - (float)b));
      *(u32*)(hil + i + 2) = hpack((f16)(v.z - (float)c), (f16)(v.w - (float)d));
    }
  } else {
    const long n = (long)KVLR_ * (H_ * 256);
    for (long i = gid * 4; i < n; i += gstep * 4) {
      float4 v = *(const float4*)(wkv + i);
      *(u32*)(wkvb + i) = pack2(v.x, v.y);
      *(u32*)(wkvb + i + 2) = pack2(v.z, v.w);
    }
  }
}

// ---------------------------------------------------------------- prep (multi-job transposes)
struct TSJob { const float* src; u16* oh; u16* ol; int K; int N; };
__global__ __launch_bounds__(256) void transpose_split_multi(
    TSJob j0, TSJob j1, TSJob j2, TSJob j3) {
  TSJob jb = (blockIdx.z == 0) ? j0 : (blockIdx.z == 1) ? j1 : (blockIdx.z == 2) ? j2 : j3;
  int k0 = blockIdx.y * 64, n0 = blockIdx.x * 64;
  if (k0 >= jb.K || n0 >= jb.N) return;
  __shared__ float t[64][65];
  for (int j = 0; j < 16; ++j) {
    int u = threadIdx.x + 256 * j; int r = u >> 6, c = u & 63;
    t[r][c] = (k0 + r < jb.K && n0 + c < jb.N) ? jb.src[(size_t)(k0 + r) * jb.N + n0 + c] : 0.f;
  }
  __syncthreads();
  for (int j = 0; j < 16; ++j) {
    int u = threadIdx.x + 256 * j; int r = u >> 6, c = u & 63;
    if (n0 + r < jb.N && k0 + c < jb.K) {
      float v = t[c][r];
      f16 h = (f16)v;
      jb.oh[(size_t)(n0 + r) * jb.K + k0 + c] = hbits(h);
      jb.ol[(size_t)(n0 + r) * jb.K + k0 + c] = hbits((f16)(v - (float)h));
    }
  }
}

struct TBJob { const float* src; u16* out; int K; int N; };
__global__ __launch_bounds__(256) void transpose_bf16_multi(TBJob j0, TBJob j1, TBJob j2) {
  TBJob jb = (blockIdx.z == 0) ? j0 : (blockIdx.z == 1) ? j1 : j2;
  int k0 = blockIdx.y * 64, n0 = blockIdx.x * 64;
  if (k0 >= jb.K || n0 >= jb.N) return;
  __shared__ float t[64][65];
  for (int j = 0; j < 16; ++j) {
    int u = threadIdx.x + 256 * j; int r = u >> 6, c = u & 63;
    t[r][c] = (k0 + r < jb.K && n0 + c < jb.N) ? jb.src[(size_t)(k0 + r) * jb.N + n0 + c] : 0.f;
  }
  __syncthreads();
  for (int j = 0; j < 16; ++j) {
    int u = threadIdx.x + 256 * j; int r = u >> 6, c = u & 63;
    if (n0 + r < jb.N && k0 + c < jb.K) jb.out[(size_t)(n0 + r) * jb.K + k0 + c] = f2bf(t[c][r]);
  }
}

// ---------------------------------------------------------------- strict GEMM (DMA-staged hi/lo)
__global__ __launch_bounds__(256) void gemm_hl(
    const u16* __restrict__ Ah_, const u16* __restrict__ Al_, int lda,
    const u16* __restrict__ Bh_, const u16* __restrict__ Bl_, int ldb,
    float* __restrict__ C, int ldc, const float* __restrict__ bias, int bcol0,
    float bscale, int N, int K) {
  __shared__ u32 Ah[128][16], Al[128][16], Bh[128][16], Bl[128][16];
  const int tid = threadIdx.x;
  const int bm = blockIdx.y * 128, bn = blockIdx.x * 128;
  const int wid = tid >> 6, lane = tid & 63, wr = wid >> 1, wc = wid & 1;
  const int lr = lane & 15, lg = lane >> 4;
  const u16* srcb = (wid == 0) ? Ah_ : (wid == 1) ? Al_ : (wid == 2) ? Bh_ : Bl_;
  const int sld = (wid < 2) ? lda : ldb;
  const int rb = (wid < 2) ? bm : bn;
  u16* dst = (u16*)((wid == 0) ? &Ah[0][0] : (wid == 1) ? &Al[0][0]
                                           : (wid == 2) ? &Bh[0][0] : &Bl[0][0]);
  const int rowl = lane >> 2;
  const int offl = (lane & 3) * 8;
  f32x4 acc[4][4] = {};
  for (int k0 = 0; k0 < K; k0 += 32) {
#pragma unroll
    for (int c = 0; c < 8; ++c) {
      int gr = rb + c * 16 + rowl;
      if (wid >= 2) gr = min(gr, N - 1);
      gload16(srcb + (size_t)gr * sld + k0 + offl, dst + c * 512);
    }
    __syncthreads();
    f16x8 ah[4], al[4], bh[4], bl[4];
#pragma unroll
    for (int i = 0; i < 4; ++i) {
      ah[i] = ldh8(&Ah[wr * 64 + i * 16 + lr][lg * 4]);
      al[i] = ldh8(&Al[wr * 64 + i * 16 + lr][lg * 4]);
      bh[i] = ldh8(&Bh[wc * 64 + i * 16 + lr][lg * 4]);
      bl[i] = ldh8(&Bl[wc * 64 + i * 16 + lr][lg * 4]);
    }
#pragma unroll
    for (int i = 0; i < 4; ++i)
#pragma unroll
      for (int jn = 0; jn < 4; ++jn) {
        acc[i][jn] = mfmah(ah[i], bh[jn], acc[i][jn]);
        acc[i][jn] = mfmah(ah[i], bl[jn], acc[i][jn]);
        acc[i][jn] = mfmah(al[i], bh[jn], acc[i][jn]);
      }
    __syncthreads();
  }
#pragma unroll
  for (int i = 0; i < 4; ++i)
#pragma unroll
    for (int jn = 0; jn < 4; ++jn)
#pragma unroll
      for (int j = 0; j < 4; ++j) {
        int row = bm + wr * 64 + i * 16 + lg * 4 + j;
        int col = bn + wc * 64 + jn * 16 + lr;
        if (col < N) {
          float v = acc[i][jn][j];
          if (col >= bcol0) v = (v + bias[col - bcol0]) * bscale;
          C[(size_t)row * ldc + col] = v;
        }
      }
}

// ---------------------------------------------------------------- tolerant bf16 GEMM (DMA-staged)
template <int CBF16>
__global__ __launch_bounds__(256) void gemm_t(
    const u16* __restrict__ Ab, int lda, long aoz,
    const u16* __restrict__ Bt, int ldb, long boz,
    void* __restrict__ Cp, int ldc, long coz, int N, int K) {
  __shared__ u32 As[128][16], Bs[128][16];
  const int tid = threadIdx.x;
  const int z = blockIdx.z;
  const int bm = blockIdx.y * 128, bn = blockIdx.x * 128;
  const int wid = tid >> 6, lane = tid & 63, wr = wid >> 1, wc = wid & 1;
  const int lr = lane & 15, lg = lane >> 4;
  const u16* A = Ab + aoz * z;
  const u16* B = Bt + boz * z;
  const u16* srcb = (wid < 2) ? A : B;
  const int sld = (wid < 2) ? lda : ldb;
  const int rb = (wid < 2) ? bm : bn;
  u16* dst = (u16*)((wid < 2) ? &As[0][0] : &Bs[0][0]);
  const int ccb = (wid & 1) * 4;
  const int rowl = lane >> 2;
  const int offl = (lane & 3) * 8;
  f32x4 acc[4][4] = {};
  for (int k0 = 0; k0 < K; k0 += 32) {
#pragma unroll
    for (int c = 0; c < 4; ++c) {
      int cc = ccb + c;
      int gr = rb + cc * 16 + rowl;
      if (wid >= 2) gr = min(gr, N - 1);
      gload16(srcb + (size_t)gr * sld + k0 + offl, dst + cc * 512);
    }
    __syncthreads();
    bf16x8 af[4], bf[4];
#pragma unroll
    for (int i = 0; i < 4; ++i) {
      af[i] = ld8(&As[wr * 64 + i * 16 + lr][lg * 4]);
      bf[i] = ld8(&Bs[wc * 64 + i * 16 + lr][lg * 4]);
    }
#pragma unroll
    for (int i = 0; i < 4; ++i)
#pragma unroll
      for (int jn = 0; jn < 4; ++jn)
        acc[i][jn] = mfma16(af[i], bf[jn], acc[i][jn]);
    __syncthreads();
  }
#pragma unroll
  for (int i = 0; i < 4; ++i)
#pragma unroll
    for (int jn = 0; jn < 4; ++jn)
#pragma unroll
      for (int j = 0; j < 4; ++j) {
        int row = bm + wr * 64 + i * 16 + lg * 4 + j;
        int col = bn + wc * 64 + jn * 16 + lr;
        if (col < N) {
          if (CBF16) ((u16*)Cp)[coz * z + (size_t)row * ldc + col] = f2bf(acc[i][jn][j]);
          else ((float*)Cp)[coz * z + (size_t)row * ldc + col] = acc[i][jn][j];
        }
      }
}

// ---------------------------------------------------------------- fused per-t norms
// rmsnorm(q) -> qcb/qch/qcl ; rmsnorm(kv) -> kv_cn ; kpe rope -> kper ;
// ki layernorm + rope -> kih/kil. All barriers reached by all 256 threads.
__global__ __launch_bounds__(256) void fused_norm_kernel(
    const float* __restrict__ qkvx, const float* __restrict__ qw,
    const float* __restrict__ kvw, const float* __restrict__ gamma,
    const float* __restrict__ beta, const float2* __restrict__ tab,
    u16* __restrict__ qcb, u16* __restrict__ qch, u16* __restrict__ qcl,
    u16* __restrict__ kv_cn, u16* __restrict__ kper,
    u16* __restrict__ kih, u16* __restrict__ kil) {
  const int t = blockIdx.x, tid = threadIdx.x;
  const float* row = qkvx + (size_t)t * QKVX_;
  __shared__ float red[256];
  __shared__ float x[128];

  // --- kpe rope (no barrier needed; independent of reductions)
  if (tid < 32) {
    const float* p = row + (QLR_ + KVLR_);
    float x0 = p[2 * tid], x1 = p[2 * tid + 1];
    rope_apply(tab[t * 32 + tid], x0, x1);
    kper[(size_t)t * ROPE_ + 2 * tid] = f2bf(x0);
    kper[(size_t)t * ROPE_ + 2 * tid + 1] = f2bf(x1);
  }

  // --- q rmsnorm
  float ss = 0.f;
  for (int i = tid; i < QLR_; i += 256) { float v = row[i]; ss += v * v; }
  red[tid] = ss; __syncthreads();
  for (int s = 128; s; s >>= 1) { if (tid < s) red[tid] += red[tid + s]; __syncthreads(); }
  float scl = 1.0f / sqrtf(red[0] / (float)QLR_ + EPS_);
  for (int i = tid; i < QLR_; i += 256) {
    float val = row[i] * scl * qw[i];
    qcb[(size_t)t * QLR_ + i] = f2bf(val);
    f16 h = (f16)val;
    qch[(size_t)t * QLR_ + i] = hbits(h);
    qcl[(size_t)t * QLR_ + i] = hbits((f16)(val - (float)h));
  }
  __syncthreads();

  // --- kv rmsnorm
  ss = 0.f;
  for (int i = tid; i < KVLR_; i += 256) { float v = row[QLR_ + i]; ss += v * v; }
  red[tid] = ss; __syncthreads();
  for (int s = 128; s; s >>= 1) { if (tid < s) red[tid] += red[tid + s]; __syncthreads(); }
  scl = 1.0f / sqrtf(red[0] / (float)KVLR_ + EPS_);
  for (int i = tid; i < KVLR_; i += 256)
    kv_cn[(size_t)t * KVLR_ + i] = f2bf(row[QLR_ + i] * scl * kvw[i]);
  __syncthreads();

  // --- ki layernorm (+rope) ; upper 128 threads contribute zeros
  float v = (tid < 128) ? row[QKVN_ + tid] : 0.f;
  red[tid] = v; __syncthreads();
  for (int s = 128; s; s >>= 1) { if (tid < s) red[tid] += red[tid + s]; __syncthreads(); }
  float mu = red[0] / 128.f;
  __syncthreads();
  float d = (tid < 128) ? (v - mu) : 0.f;
  red[tid] = d * d; __syncthreads();
  for (int s = 128; s; s >>= 1) { if (tid < s) red[tid] += red[tid + s]; __syncthreads(); }
  float var = red[0] / 128.f;
  if (tid < 128) x[tid] = d * (1.0f / sqrtf(var + EPS_)) * gamma[tid] + beta[tid];
  __syncthreads();
  if (tid < 32) {
    float x0 = x[2 * tid], x1 = x[2 * tid + 1];
    rope_apply(tab[t * 32 + tid], x0, x1);
    x[2 * tid] = x0; x[2 * tid + 1] = x1;
  }
  __syncthreads();
  if (tid < 128) {
    float fv = x[tid];
    f16 h = (f16)fv;
    kih[(size_t)t * IDXD_ + tid] = hbits(h);
    kil[(size_t)t * IDXD_ + tid] = hbits((f16)(fv - (float)h));
  }
}

// ---------------------------------------------------------------- rope users (table-driven)
__global__ __launch_bounds__(256) void rope_qi_split_kernel(
    const float* __restrict__ qi, const float2* __restrict__ tab,
    u16* __restrict__ qih, u16* __restrict__ qil) {
  const int t = blockIdx.x, tid = threadIdx.x;
  const float* src = qi + (size_t)t * (IDXH_ * IDXD_);
  u16* dh = qih + (size_t)t * (IDXH_ * IDXD_);
  u16* dl = qil + (size_t)t * (IDXH_ * IDXD_);
  for (int p = tid; p < IDXH_ * IDXD_ / 2; p += 256) {
    int d = p & 63;
    float x0 = src[2 * p], x1 = src[2 * p + 1];
    if (d < 32) rope_apply(tab[t * 32 + d], x0, x1);
    f16 h0 = (f16)x0, h1 = (f16)x1;
    *(u32*)(dh + 2 * p) = hpack(h0, h1);
    *(u32*)(dl + 2 * p) = hpack((f16)(x0 - (float)h0), (f16)(x1 - (float)h1));
  }
}

__global__ __launch_bounds__(256) void rope_q_bf_kernel(
    u16* __restrict__ qfb, const float2* __restrict__ tab) {
  const int t = blockIdx.x, tid = threadIdx.x;
  for (int idx = tid; idx < H_ * 32; idx += 256) {
    int hh = idx / 32, j = idx % 32;
    u16* p = qfb + (size_t)t * (H_ * QKD_) + hh * QKD_ + NOPE_ + 2 * j;
    float x0 = bf2f(p[0]), x1 = bf2f(p[1]);
    rope_apply(tab[t * 32 + j], x0, x1);
    p[0] = f2bf(x0); p[1] = f2bf(x1);
  }
}

// ---------------------------------------------------------------- indexer score (pre-split f16 MFMA)
__global__ __launch_bounds__(256) void score_mfma(
    const u16* __restrict__ qih, const u16* __restrict__ qil,
    const u16* __restrict__ kih, const u16* __restrict__ kil,
    const float* __restrict__ wgt, int ldw, float* __restrict__ score) {
  const int s0 = blockIdx.x * 64, t0 = blockIdx.y * 64;
  if (s0 > t0 + 63) return;
  __shared__ u32 Kh[64][68], Kl[64][68], Qh[64][68], Ql[64][68];
  __shared__ float wts[64][33];
  const int tid = threadIdx.x;
  const int wid = tid >> 6, lane = tid & 63, wr = wid >> 1, wc = wid & 1;
  const int lr = lane & 15, lg = lane >> 4;
#pragma unroll
  for (int j = 0; j < 4; ++j) {
    int u = tid + 256 * j; int row = u >> 4, p = u & 15;
    *(uint4*)&Kh[row][p * 4] = *(const uint4*)(kih + (size_t)(s0 + row) * IDXD_ + p * 8);
    *(uint4*)&Kl[row][p * 4] = *(const uint4*)(kil + (size_t)(s0 + row) * IDXD_ + p * 8);
  }
#pragma unroll
  for (int j = 0; j < 8; ++j) {
    int u = tid + 256 * j; int r = u >> 5, c = u & 31;
    wts[r][c] = wgt[(size_t)(t0 + r) * ldw + c];
  }
  __syncthreads();
  f16x8 bh[2][4], bl[2][4];
#pragma unroll
  for (int ni = 0; ni < 2; ++ni)
#pragma unroll
    for (int kb = 0; kb < 4; ++kb) {
      bh[ni][kb] = ldh8(&Kh[wc * 32 + ni * 16 + lr][kb * 16 + lg * 4]);
      bl[ni][kb] = ldh8(&Kl[wc * 32 + ni * 16 + lr][kb * 16 + lg * 4]);
    }
  f32x4 fin[2][2] = {};
  for (int h = 0; h < IDXH_; ++h) {
#pragma unroll
    for (int j = 0; j < 4; ++j) {
      int u = tid + 256 * j; int row = u >> 4, p = u & 15;
      size_t g = (size_t)(t0 + row) * (IDXH_ * IDXD_) + h * IDXD_ + p * 8;
      *(uint4*)&Qh[row][p * 4] = *(const uint4*)(qih + g);
      *(uint4*)&Ql[row][p * 4] = *(const uint4*)(qil + g);
    }
    __syncthreads();
    f32x4 acch[2][2] = {};
#pragma unroll
    for (int kb = 0; kb < 4; ++kb) {
      f16x8 ah0 = ldh8(&Qh[wr * 32 + lr][kb * 16 + lg * 4]);
      f16x8 ah1 = ldh8(&Qh[wr * 32 + 16 + lr][kb * 16 + lg * 4]);
      f16x8 al0 = ldh8(&Ql[wr * 32 + lr][kb * 16 + lg * 4]);
      f16x8 al1 = ldh8(&Ql[wr * 32 + 16 + lr][kb * 16 + lg * 4]);
#pragma unroll
      for (int ni = 0; ni < 2; ++ni) {
        acch[0][ni] = mfmah(ah0, bh[ni][kb], acch[0][ni]);
        acch[0][ni] = mfmah(ah0, bl[ni][kb], acch[0][ni]);
        acch[0][ni] = mfmah(al0, bh[ni][kb], acch[0][ni]);
        acch[1][ni] = mfmah(ah1, bh[ni][kb], acch[1][ni]);
        acch[1][ni] = mfmah(ah1, bl[ni][kb], acch[1][ni]);
        acch[1][ni] = mfmah(al1, bh[ni][kb], acch[1][ni]);
      }
    }
#pragma unroll
    for (int mi = 0; mi < 2; ++mi)
#pragma unroll
      for (int j = 0; j < 4; ++j) {
        float w = wts[wr * 32 + mi * 16 + lg * 4 + j][h];
        fin[mi][0][j] += w * fmaxf(acch[mi][0][j], 0.f);
        fin[mi][1][j] += w * fmaxf(acch[mi][1][j], 0.f);
      }
    __syncthreads();
  }
#pragma unroll
  for (int mi = 0; mi < 2; ++mi)
#pragma unroll
    for (int ni = 0; ni < 2; ++ni)
#pragma unroll
      for (int j = 0; j < 4; ++j) {
        int row = t0 + wr * 32 + mi * 16 + lg * 4 + j;
        int col = s0 + wc * 32 + ni * 16 + lr;
        score[(size_t)row * T_ + col] = fin[mi][ni][j];
      }
}

// ---------------------------------------------------------------- top-k (exact, 4-bit radix)
__global__ __launch_bounds__(256) void topk_kernel(
    const float* __restrict__ score, int* __restrict__ selidx,
    int* __restrict__ selcnt) {
  const int t = blockIdx.x;
  const int L = t + 1;
  const int tid = threadIdx.x;
  if (L <= TOPK_) {
    for (int j = tid; j < TOPK_; j += 256)
      selidx[(size_t)t * TOPK_ + j] = (j < L) ? j : 0;
    if (tid == 0) selcnt[t] = L;
    return;
  }
  __shared__ unsigned u[T_];
  __shared__ unsigned hist[16];
  __shared__ unsigned sprefix;
  __shared__ int sk;
  __shared__ int part[256];
  for (int i = tid; i < T_; i += 256) {
    float v = (i < L) ? score[(size_t)t * T_ + i] : -FLT_MAX;
    unsigned b = __float_as_uint(v);
    u[i] = (b & 0x80000000u) ? ~b : (b | 0x80000000u);
  }
  if (tid == 0) { sprefix = 0u; sk = TOPK_; }
  __syncthreads();
  for (int pass = 0; pass < 8; ++pass) {
    const int shift = 28 - 4 * pass;
    if (tid < 16) hist[tid] = 0u;
    __syncthreads();
    unsigned pfx = sprefix;
    for (int i = tid; i < L; i += 256) {
      unsigned val = u[i];
      bool match = (pass == 0) || ((val >> (shift + 4)) == pfx);
      if (match) atomicAdd(&hist[(val >> shift) & 15u], 1u);
    }
    __syncthreads();
    if (tid == 0) {
      int k = sk; unsigned cum = 0u; int bsel = 0;
      for (int bb = 15; bb >= 0; --bb) {
        if (cum + hist[bb] >= (unsigned)k) { bsel = bb; sk = k - (int)cum; break; }
        cum += hist[bb];
      }
      sprefix = (sprefix << 4) | (unsigned)bsel;
    }
    __syncthreads();
  }
  const unsigned thr = sprefix;
  const int kEq = sk;
  const int base = tid * 8;
  int eqloc[8]; int esum = 0;
  for (int r = 0; r < 8; ++r) {
    int i = base + r;
    int f = (i < L && u[i] == thr) ? 1 : 0;
    eqloc[r] = esum; esum += f;
  }
  part[tid] = esum; __syncthreads();
  for (int off = 1; off < 256; off <<= 1) {
    int v = (tid >= off) ? part[tid - off] : 0;
    __syncthreads();
    part[tid] += v;
    __syncthreads();
  }
  const int ebase = (tid > 0) ? part[tid - 1] : 0;
  __syncthreads();
  int sloc[8], selflag[8]; int ssum = 0;
  for (int r = 0; r < 8; ++r) {
    int i = base + r;
    int f = 0;
    if (i < L) {
      unsigned ui = u[i];
      if (ui > thr) f = 1;
      else if (ui == thr && (ebase + eqloc[r]) < kEq) f = 1;
    }
    selflag[r] = f; sloc[r] = ssum; ssum += f;
  }
  part[tid] = ssum; __syncthreads();
  for (int off = 1; off < 256; off <<= 1) {
    int v = (tid >= off) ? part[tid - off] : 0;
    __syncthreads();
    part[tid] += v;
    __syncthreads();
  }
  const int sbase = (tid > 0) ? part[tid - 1] : 0;
  for (int r = 0; r < 8; ++r)
    if (selflag[r]) selidx[(size_t)t * TOPK_ + sbase + sloc[r]] = base + r;
  if (tid == 0) selcnt[t] = TOPK_;
}

// ---------------------------------------------------------------- MLA attention v8
__global__ __launch_bounds__(256, 3) void attn_mla_kernel(
    const u16* __restrict__ qeff, const u16* __restrict__ qfb,
    const u16* __restrict__ kvcn, const u16* __restrict__ kper,
    const int* __restrict__ selidx, const int* __restrict__ selcnt,
    u16* __restrict__ Olat) {
  const int t = blockIdx.x;
  const int tid = threadIdx.x;
  const int wid = tid >> 6, lane = tid & 63;
  const int lr = lane & 15, lg = lane >> 4;
  __shared__ int sidxs[512];
  __shared__ u16 Pb[16][520];
  __shared__ __align__(16) u16 SB[4][4224];  // QK: 2 x 2048-u16 bufs; PV: u32[16][132]
  __shared__ float redm[4][16];
  __shared__ float reds[4][16];
  const int cnt = selcnt[t];
  for (int j = tid; j < 512; j += 256) sidxs[j] = selidx[(size_t)t * TOPK_ + j];
  __syncthreads();

  const int kl = lane >> 2;
  const int pcs = (((lane & 3) ^ ((lane >> 3) & 3))) << 3;
  const int rsw = ((lr >> 1) & 3) << 3;
  int skey[8];
#pragma unroll
  for (int j = 0; j < 8; ++j) skey[j] = sidxs[wid * 128 + j * 16 + kl];
  u16* buf0 = &SB[wid][0];
  u16* buf1 = &SB[wid][2048];

  const u16* qe = qeff + (size_t)t * (H_ * 512) + lr * 512 + lg * 8;
  const u16* qp = qfb + (size_t)t * (H_ * QKD_) + lr * QKD_ + NOPE_ + lg * 8;
  bf16x8 qf[18];
#pragma unroll
  for (int kb = 0; kb < 16; ++kb) qf[kb] = ld8(qe + kb * 32);
  qf[16] = ld8(qp);
  qf[17] = ld8(qp + 32);

  f32x4 lgv[8] = {};
#pragma unroll
  for (int j = 0; j < 4; ++j)
    gload16(kvcn + (size_t)skey[j] * 512 + pcs, buf0 + j * 512);
#pragma unroll
  for (int j = 0; j < 4; ++j)
    gload16(kvcn + (size_t)skey[4 + j] * 512 + pcs, buf1 + j * 512);
#pragma unroll
  for (int s = 0; s < 36; ++s) {
    const int kb = s >> 1, h = s & 1;
    u16* b = (h == 0) ? buf0 : buf1;
    if (s == 35) { asm volatile("s_waitcnt vmcnt(0)" ::: "memory"); }
    else         { asm volatile("s_waitcnt vmcnt(4)" ::: "memory"); }
    __builtin_amdgcn_sched_barrier(0);
    bf16x8 kf[4];
#pragma unroll
    for (int i = 0; i < 4; ++i)
      kf[i] = ld8(b + (i * 16 + lr) * 32 + (lg * 8 ^ rsw));
#pragma unroll
    for (int i = 0; i < 4; ++i)
      lgv[h * 4 + i] = mfma16(kf[i], qf[kb], lgv[h * 4 + i]);
    asm volatile("s_waitcnt lgkmcnt(0)" ::: "memory");
    __builtin_amdgcn_sched_barrier(0);
    if (s + 2 < 36) {
      const int kb2 = (s + 2) >> 1;
      if (kb2 < 16) {
#pragma unroll
        for (int j = 0; j < 4; ++j)
          gload16(kvcn + (size_t)skey[h * 4 + j] * 512 + kb2 * 32 + pcs, b + j * 512);
      } else {
#pragma unroll
        for (int j = 0; j < 4; ++j)
          gload16(kper + (size_t)skey[h * 4 + j] * 64 + (kb2 - 16) * 32 + pcs, b + j * 512);
      }
    }
  }

  float mx = -FLT_MAX;
#pragma unroll
  for (int m = 0; m < 8; ++m)
#pragma unroll
    for (int j = 0; j < 4; ++j) {
      int slot = wid * 128 + m * 16 + lg * 4 + j;
      float v = (slot < cnt) ? lgv[m][j] * SCALING_ : -FLT_MAX;
      lgv[m][j] = v;
      mx = fmaxf(mx, v);
    }
  mx = fmaxf(mx, __shfl_xor(mx, 16));
  mx = fmaxf(mx, __shfl_xor(mx, 32));
  if (lane < 16) redm[wid][lane] = mx;
  __syncthreads();
  float hm = fmaxf(fmaxf(redm[0][lr], redm[1][lr]), fmaxf(redm[2][lr], redm[3][lr]));
  float sm = 0.f;
#pragma unroll
  for (int m = 0; m < 8; ++m)
#pragma unroll
    for (int j = 0; j < 4; ++j) {
      int slot = wid * 128 + m * 16 + lg * 4 + j;
      float e = (slot < cnt) ? expf(lgv[m][j] - hm) : 0.f;
      lgv[m][j] = e; sm += e;
    }
  sm += __shfl_xor(sm, 16);
  sm += __shfl_xor(sm, 32);
  if (lane < 16) reds[wid][lane] = sm;
  __syncthreads();
  float inv = 1.f / (reds[0][lr] + reds[1][lr] + reds[2][lr] + reds[3][lr]);
#pragma unroll
  for (int m = 0; m < 8; ++m) {
    int sl = wid * 128 + m * 16 + lg * 4;
    *(u32*)&Pb[lr][sl] = pack2(lgv[m][0] * inv, lgv[m][1] * inv);
    *(u32*)&Pb[lr][sl + 2] = pack2(lgv[m][2] * inv, lgv[m][3] * inv);
  }
  __syncthreads();

  u32* vpw = (u32*)&SB[wid][0];
  const int pl = lane >> 4;
  const int gq = lane & 15;
  const u16* vsrc = kvcn + wid * 128 + gq * 8;
  f32x4 oacc[8] = {};
  uint4 ra[4], rb[4];
#pragma unroll
  for (int s = 0; s < 4; ++s) {
    int p = s * 4 + pl;
    ra[s] = *(const uint4*)(vsrc + (size_t)sidxs[2 * p] * 512);
    rb[s] = *(const uint4*)(vsrc + (size_t)sidxs[2 * p + 1] * 512);
  }
  for (int c = 0; c < 16; ++c) {
#pragma unroll
    for (int s = 0; s < 4; ++s) {
      int p = s * 4 + pl;
      int col = (gq * 8) ^ ((s & 3) << 3);
      const u16* A = (const u16*)&ra[s];
      const u16* B = (const u16*)&rb[s];
      u32 w[8];
#pragma unroll
      for (int j = 0; j < 8; ++j) w[j] = (u32)A[j] | ((u32)B[j] << 16);
      *(uint4*)&vpw[p * 132 + col] = make_uint4(w[0], w[1], w[2], w[3]);
      *(uint4*)&vpw[p * 132 + col + 4] = make_uint4(w[4], w[5], w[6], w[7]);
    }
    if (c < 15) {
#pragma unroll
      for (int s = 0; s < 4; ++s) {
        int p = s * 4 + pl;
        ra[s] = *(const uint4*)(vsrc + (size_t)sidxs[(c + 1) * 32 + 2 * p] * 512);
        rb[s] = *(const uint4*)(vsrc + (size_t)sidxs[(c + 1) * 32 + 2 * p + 1] * 512);
      }
    }
    bf16x8 pa = ld8(&Pb[lr][c * 32 + lg * 8]);
    union BB { u32 u[4]; bf16x8 v; };
    BB bb[8];
#pragma unroll
    for (int C = 0; C < 8; ++C) {
      int col = (C * 16 + lr) ^ (lg << 3);
#pragma unroll
      for (int e = 0; e < 4; ++e)
        bb[C].u[e] = vpw[(lg * 4 + e) * 132 + col];
    }
    __builtin_amdgcn_s_setprio(1);
#pragma unroll
    for (int C = 0; C < 8; ++C) oacc[C] = mfma16(pa, bb[C].v, oacc[C]);
    __builtin_amdgcn_s_setprio(0);
  }
#pragma unroll
  for (int C = 0; C < 8; ++C)
#pragma unroll
    for (int j = 0; j < 4; ++j) {
      int h = lg * 4 + j;
      Olat[(size_t)t * (H_ * 512) + h * 512 + wid * 128 + C * 16 + lr] = f2bf(oacc[C][j]);
    }
}

// ---------------------------------------------------------------- launch
extern "C" void kernel_launch(void* const* d_in, const int* in_sizes, int n_in,
                              void* d_out, int out_size, void* d_ws, size_t ws_size,
                              hipStream_t stream) {
  const float* hidden    = (const float*)d_in[1];
  const float* w_qkv_a   = (const float*)d_in[2];
  const float* q_a_ln_w  = (const float*)d_in[3];
  const float* w_qb      = (const float*)d_in[4];
  const float* kv_a_ln_w = (const float*)d_in[5];
  const float* w_kvb     = (const float*)d_in[6];
  const float* w_o       = (const float*)d_in[7];
  const float* w_idx_qb  = (const float*)d_in[8];
  const float* w_idx_k   = (const float*)d_in[9];
  const float* idx_g     = (const float*)d_in[10];
  const float* idx_b     = (const float*)d_in[11];
  const float* w_wproj   = (const float*)d_in[12];
  const float* b_wproj   = (const float*)d_in[13];

  char* W = (char*)d_ws;
  size_t o = 0;
  auto alloc = [&](size_t bytes) { void* p = W + o; o += (bytes + 255) & ~(size_t)255; return p; };
  u16* qcb     = (u16*)alloc((size_t)T_ * QLR_ * 2);
  u16* kv_cn   = (u16*)alloc((size_t)T_ * KVLR_ * 2);
  u16* kper    = (u16*)alloc((size_t)T_ * ROPE_ * 2);
  int* selidx  = (int*)alloc((size_t)T_ * TOPK_ * 4);
  int* selcnt  = (int*)alloc((size_t)T_ * 4);
  u16* kih     = (u16*)alloc((size_t)T_ * IDXD_ * 2);
  u16* kil     = (u16*)alloc((size_t)T_ * IDXD_ * 2);
  u16* hidh    = (u16*)alloc((size_t)T_ * HID_ * 2);
  u16* hidl    = (u16*)alloc((size_t)T_ * HID_ * 2);
  float2* rtab = (float2*)alloc((size_t)T_ * 32 * 8);
  u16* qch     = (u16*)alloc((size_t)T_ * QLR_ * 2);
  u16* qcl     = (u16*)alloc((size_t)T_ * QLR_ * 2);
  u16* wiqh    = (u16*)alloc((size_t)(IDXH_ * IDXD_) * QLR_ * 2);
  u16* wiql    = (u16*)alloc((size_t)(IDXH_ * IDXD_) * QLR_ * 2);
  u16* qih     = qch;
  u16* qil     = qch + (size_t)T_ * IDXH_ * IDXD_;
  float* qi    = (float*)alloc((size_t)T_ * IDXH_ * IDXD_ * 4);
  u16* qeff    = (u16*)qi;
  float* score = (float*)alloc((size_t)T_ * T_ * 4);
  u16* qfb     = (u16*)score;
  u16* attno   = (u16*)score;
  u16* wcath   = (u16*)alloc((size_t)QKVX_ * HID_ * 2);
  u16* wcatl   = (u16*)alloc((size_t)QKVX_ * HID_ * 2);
  float* qkvx  = (float*)alloc((size_t)T_ * QKVX_ * 4);
  u16* Olat    = wcath;
  u16* wqbt    = (u16*)alloc((size_t)(H_ * QKD_) * QLR_ * 2);
  u16* wkvb    = (u16*)alloc((size_t)KVLR_ * (H_ * 256) * 2);
  u16* wkvbt   = (u16*)alloc((size_t)(H_ * 256) * KVLR_ * 2);
  u16* wot     = (u16*)alloc((size_t)(H_ * VD_) * HID_ * 2);

  dim3 blk(256);
  auto g2 = [](int M, int N, int Z) { return dim3((N + 127) / 128, M / 128, Z); };

  prep_elem_multi<<<dim3(1024, 1, 3), blk, 0, stream>>>(
      rtab, hidden, hidh, hidl, w_kvb, wkvb);
  {
    TSJob j0{w_qkv_a, wcath, wcatl, HID_, QKVN_};
    TSJob j1{w_idx_qb, wiqh, wiql, QLR_, IDXH_ * IDXD_};
    TSJob j2{w_idx_k, wcath + (size_t)QKVN_ * HID_, wcatl + (size_t)QKVN_ * HID_, HID_, IDXD_};
    TSJob j3{w_wproj, wcath + (size_t)(QKVN_ + IDXD_) * HID_, wcatl + (size_t)(QKVN_ + IDXD_) * HID_, HID_, IDXH_};
    transpose_split_multi<<<dim3(64, 32, 4), blk, 0, stream>>>(j0, j1, j2, j3);
  }
  {
    TBJob j0{w_qb, wqbt, QLR_, H_ * QKD_};
    TBJob j1{w_kvb, wkvbt, KVLR_, H_ * 256};
    TBJob j2{w_o, wot, H_ * VD_, HID_};
    transpose_bf16_multi<<<dim3(64, 32, 3), blk, 0, stream>>>(j0, j1, j2);
  }

  gemm_hl<<<g2(T_, QKVX_, 1), blk, 0, stream>>>(
      hidh, hidl, HID_, wcath, wcatl, HID_, qkvx, QKVX_,
      b_wproj, QKVN_ + IDXD_, 0.015625f, QKVX_, HID_);
  fused_norm_kernel<<<T_, blk, 0, stream>>>(
      qkvx, q_a_ln_w, kv_a_ln_w, idx_g, idx_b, rtab,
      qcb, qch, qcl, kv_cn, kper, kih, kil);

  gemm_hl<<<g2(T_, IDXH_ * IDXD_, 1), blk, 0, stream>>>(
      qch, qcl, QLR_, wiqh, wiql, QLR_, qi, IDXH_ * IDXD_,
      nullptr, 1 << 30, 1.f, IDXH_ * IDXD_, QLR_);
  rope_qi_split_kernel<<<T_, blk, 0, stream>>>(qi, rtab, qih, qil);

  score_mfma<<<dim3(32, 32), blk, 0, stream>>>(qih, qil, kih, kil,
                                               qkvx + QKVN_ + IDXD_, QKVX_, score);
  topk_kernel<<<T_, blk, 0, stream>>>(score, selidx, selcnt);

  gemm_t<1><<<g2(T_, H_ * QKD_, 1), blk, 0, stream>>>(qcb, QLR_, 0, wqbt, QLR_, 0, qfb, H_ * QKD_, 0, H_ * QKD_, QLR_);
  rope_q_bf_kernel<<<T_, blk, 0, stream>>>(qfb, rtab);
  gemm_t<1><<<g2(T_, 512, H_), blk, 0, stream>>>(qfb, H_ * QKD_, QKD_, wkvb, H_ * 256, 256, qeff, H_ * 512, 512, 512, NOPE_);
  attn_mla_kernel<<<T_, blk, 0, stream>>>(qeff, qfb, kv_cn, kper, selidx, selcnt, Olat);
  gemm_t<1><<<g2(T_, VD_, H_), blk, 0, stream>>>(Olat, H_ * 512, 512, wkvbt + 128 * 512, KVLR_, 256 * 512, attno, H_ * VD_, VD_, VD_, 512);
  gemm_t<0><<<g2(T_, HID_, 1), blk, 0, stream>>>(attno, H_ * VD_, 0, wot, H_ * VD_, 0, d_out, HID_, 0, HID_, H_ * VD_);
}

// Round 21
// 641.597 us; speedup vs baseline: 1.0767x; 1.0134x over previous
//
#include <hip/hip_runtime.h>
#include <cfloat>
#include <cmath>

#define T_    2048
#define HID_  2048
#define QKVN_ 2112
#define QKVX_ 2272   // fused: 2112 qkv | 128 ki | 32 wgt
#define QLR_  1536
#define KVLR_ 512
#define ROPE_ 64
#define NOPE_ 128
#define QKD_  192
#define VD_   128
#define H_    16
#define IDXH_ 32
#define IDXD_ 128
#define TOPK_ 512
#define EPS_  1e-6f
#define SCALING_ 0.07216878364870323f   // 192^-0.5

typedef unsigned int u32;
typedef unsigned short u16;
typedef __bf16 bf16x8 __attribute__((ext_vector_type(8)));
typedef _Float16 f16;
typedef f16 f16x8 __attribute__((ext_vector_type(8)));
typedef float f32x4 __attribute__((ext_vector_type(4)));

__device__ __forceinline__ u16 f2bf(float x) {
  u32 u = __float_as_uint(x);
  u32 r = (u + 0x7fffu + ((u >> 16) & 1u)) >> 16;
  return (u16)r;
}
__device__ __forceinline__ float bf2f(u16 h) { return __uint_as_float(((u32)h) << 16); }
__device__ __forceinline__ u32 pack2(float a, float b) { return (u32)f2bf(a) | ((u32)f2bf(b) << 16); }
__device__ __forceinline__ bf16x8 ld8(const void* p) { return *(const bf16x8*)p; }
__device__ __forceinline__ f32x4 mfma16(bf16x8 a, bf16x8 b, f32x4 c) {
  return __builtin_amdgcn_mfma_f32_16x16x32_bf16(a, b, c, 0, 0, 0);
}
__device__ __forceinline__ u16 hbits(f16 h) { union { f16 h; u16 u; } c; c.h = h; return c.u; }
__device__ __forceinline__ u32 hpack(f16 a, f16 b) { return (u32)hbits(a) | ((u32)hbits(b) << 16); }
__device__ __forceinline__ f16x8 ldh8(const void* p) { return *(const f16x8*)p; }
__device__ __forceinline__ f32x4 mfmah(f16x8 a, f16x8 b, f32x4 c) {
  return __builtin_amdgcn_mfma_f32_16x16x32_f16(a, b, c, 0, 0, 0);
}
__device__ __forceinline__ void gload16(const u16* g, u16* l) {
  __builtin_amdgcn_global_load_lds(
      (__attribute__((address_space(1))) void*)(g),
      (__attribute__((address_space(3))) void*)(l), 16, 0, 0);
}

__device__ __forceinline__ void rope_apply(float2 cs, float& x0, float& x1) {
  float a = x0, b = x1;
  x0 = a * cs.x - b * cs.y;
  x1 = a * cs.y + b * cs.x;
}

// ---------------------------------------------------------------- prep elementwise (multi-job)
__global__ __launch_bounds__(256) void prep_elem_multi(
    float2* __restrict__ tab,
    const float* __restrict__ hid, u16* __restrict__ hih, u16* __restrict__ hil,
    const float* __restrict__ wkv, u16* __restrict__ wkvb) {
  const long gid = (long)blockIdx.x * 256 + threadIdx.x;
  const long gstep = (long)gridDim.x * 256;
  if (blockIdx.z == 0) {
    for (long i = gid; i < (long)T_ * 32; i += gstep) {
      int t = (int)(i >> 5), j = (int)(i & 31);
      float inv = powf(10000.f, -(float)j * (1.f / 32.f));
      float f = (float)t * inv;
      tab[i] = make_float2(cosf(f), sinf(f));
    }
  } else if (blockIdx.z == 1) {
    const long n = (long)T_ * HID_;
    for (long i = gid * 4; i < n; i += gstep * 4) {
      float4 v = *(const float4*)(hid + i);
      f16 a = (f16)v.x, b = (f16)v.y, c = (f16)v.z, d = (f16)v.w;
      *(u32*)(hih + i) = hpack(a, b);
      *(u32*)(hih + i + 2) = hpack(c, d);
      *(u32*)(hil + i) = hpack((f16)(v.x - (float)a), (f16)(v.y - (float)b));
      *(u32*)(hil + i + 2) = hpack((f16)(v.z - (float)c), (f16)(v.w - (float)d));
    }
  } else {
    const long n = (long)KVLR_ * (H_ * 256);
    for (long i = gid * 4; i < n; i += gstep * 4) {
      float4 v = *(const float4*)(wkv + i);
      *(u32*)(wkvb + i) = pack2(v.x, v.y);
      *(u32*)(wkvb + i + 2) = pack2(v.z, v.w);
    }
  }
}

// ---------------------------------------------------------------- prep (multi-job transposes)
struct TSJob { const float* src; u16* oh; u16* ol; int K; int N; };
__global__ __launch_bounds__(256) void transpose_split_multi(
    TSJob j0, TSJob j1, TSJob j2, TSJob j3) {
  TSJob jb = (blockIdx.z == 0) ? j0 : (blockIdx.z == 1) ? j1 : (blockIdx.z == 2) ? j2 : j3;
  int k0 = blockIdx.y * 64, n0 = blockIdx.x * 64;
  if (k0 >= jb.K || n0 >= jb.N) return;
  __shared__ float t[64][65];
  for (int j = 0; j < 16; ++j) {
    int u = threadIdx.x + 256 * j; int r = u >> 6, c = u & 63;
    t[r][c] = (k0 + r < jb.K && n0 + c < jb.N) ? jb.src[(size_t)(k0 + r) * jb.N + n0 + c] : 0.f;
  }
  __syncthreads();
  for (int j = 0; j < 16; ++j) {
    int u = threadIdx.x + 256 * j; int r = u >> 6, c = u & 63;
    if (n0 + r < jb.N && k0 + c < jb.K) {
      float v = t[c][r];
      f16 h = (f16)v;
      jb.oh[(size_t)(n0 + r) * jb.K + k0 + c] = hbits(h);
      jb.ol[(size_t)(n0 + r) * jb.K + k0 + c] = hbits((f16)(v - (float)h));
    }
  }
}

struct TBJob { const float* src; u16* out; int K; int N; };
__global__ __launch_bounds__(256) void transpose_bf16_multi(TBJob j0, TBJob j1, TBJob j2) {
  TBJob jb = (blockIdx.z == 0) ? j0 : (blockIdx.z == 1) ? j1 : j2;
  int k0 = blockIdx.y * 64, n0 = blockIdx.x * 64;
  if (k0 >= jb.K || n0 >= jb.N) return;
  __shared__ float t[64][65];
  for (int j = 0; j < 16; ++j) {
    int u = threadIdx.x + 256 * j; int r = u >> 6, c = u & 63;
    t[r][c] = (k0 + r < jb.K && n0 + c < jb.N) ? jb.src[(size_t)(k0 + r) * jb.N + n0 + c] : 0.f;
  }
  __syncthreads();
  for (int j = 0; j < 16; ++j) {
    int u = threadIdx.x + 256 * j; int r = u >> 6, c = u & 63;
    if (n0 + r < jb.N && k0 + c < jb.K) jb.out[(size_t)(n0 + r) * jb.K + k0 + c] = f2bf(t[c][r]);
  }
}

// ---------------------------------------------------------------- strict GEMM (DMA-staged hi/lo)
__global__ __launch_bounds__(256) void gemm_hl(
    const u16* __restrict__ Ah_, const u16* __restrict__ Al_, int lda,
    const u16* __restrict__ Bh_, const u16* __restrict__ Bl_, int ldb,
    float* __restrict__ C, int ldc, const float* __restrict__ bias, int bcol0,
    float bscale, int N, int K) {
  __shared__ u32 Ah[128][16], Al[128][16], Bh[128][16], Bl[128][16];
  const int tid = threadIdx.x;
  const int bm = blockIdx.y * 128, bn = blockIdx.x * 128;
  const int wid = tid >> 6, lane = tid & 63, wr = wid >> 1, wc = wid & 1;
  const int lr = lane & 15, lg = lane >> 4;
  const u16* srcb = (wid == 0) ? Ah_ : (wid == 1) ? Al_ : (wid == 2) ? Bh_ : Bl_;
  const int sld = (wid < 2) ? lda : ldb;
  const int rb = (wid < 2) ? bm : bn;
  u16* dst = (u16*)((wid == 0) ? &Ah[0][0] : (wid == 1) ? &Al[0][0]
                                           : (wid == 2) ? &Bh[0][0] : &Bl[0][0]);
  const int rowl = lane >> 2;
  const int offl = (lane & 3) * 8;
  f32x4 acc[4][4] = {};
  for (int k0 = 0; k0 < K; k0 += 32) {
#pragma unroll
    for (int c = 0; c < 8; ++c) {
      int gr = rb + c * 16 + rowl;
      if (wid >= 2) gr = min(gr, N - 1);
      gload16(srcb + (size_t)gr * sld + k0 + offl, dst + c * 512);
    }
    __syncthreads();
    f16x8 ah[4], al[4], bh[4], bl[4];
#pragma unroll
    for (int i = 0; i < 4; ++i) {
      ah[i] = ldh8(&Ah[wr * 64 + i * 16 + lr][lg * 4]);
      al[i] = ldh8(&Al[wr * 64 + i * 16 + lr][lg * 4]);
      bh[i] = ldh8(&Bh[wc * 64 + i * 16 + lr][lg * 4]);
      bl[i] = ldh8(&Bl[wc * 64 + i * 16 + lr][lg * 4]);
    }
#pragma unroll
    for (int i = 0; i < 4; ++i)
#pragma unroll
      for (int jn = 0; jn < 4; ++jn) {
        acc[i][jn] = mfmah(ah[i], bh[jn], acc[i][jn]);
        acc[i][jn] = mfmah(ah[i], bl[jn], acc[i][jn]);
        acc[i][jn] = mfmah(al[i], bh[jn], acc[i][jn]);
      }
    __syncthreads();
  }
#pragma unroll
  for (int i = 0; i < 4; ++i)
#pragma unroll
    for (int jn = 0; jn < 4; ++jn)
#pragma unroll
      for (int j = 0; j < 4; ++j) {
        int row = bm + wr * 64 + i * 16 + lg * 4 + j;
        int col = bn + wc * 64 + jn * 16 + lr;
        if (col < N) {
          float v = acc[i][jn][j];
          if (col >= bcol0) v = (v + bias[col - bcol0]) * bscale;
          C[(size_t)row * ldc + col] = v;
        }
      }
}

// ---------------------------------------------------------------- tolerant bf16 GEMM (DMA-staged)
template <int CBF16>
__global__ __launch_bounds__(256) void gemm_t(
    const u16* __restrict__ Ab, int lda, long aoz,
    const u16* __restrict__ Bt, int ldb, long boz,
    void* __restrict__ Cp, int ldc, long coz, int N, int K) {
  __shared__ u32 As[128][16], Bs[128][16];
  const int tid = threadIdx.x;
  const int z = blockIdx.z;
  const int bm = blockIdx.y * 128, bn = blockIdx.x * 128;
  const int wid = tid >> 6, lane = tid & 63, wr = wid >> 1, wc = wid & 1;
  const int lr = lane & 15, lg = lane >> 4;
  const u16* A = Ab + aoz * z;
  const u16* B = Bt + boz * z;
  const u16* srcb = (wid < 2) ? A : B;
  const int sld = (wid < 2) ? lda : ldb;
  const int rb = (wid < 2) ? bm : bn;
  u16* dst = (u16*)((wid < 2) ? &As[0][0] : &Bs[0][0]);
  const int ccb = (wid & 1) * 4;
  const int rowl = lane >> 2;
  const int offl = (lane & 3) * 8;
  f32x4 acc[4][4] = {};
  for (int k0 = 0; k0 < K; k0 += 32) {
#pragma unroll
    for (int c = 0; c < 4; ++c) {
      int cc = ccb + c;
      int gr = rb + cc * 16 + rowl;
      if (wid >= 2) gr = min(gr, N - 1);
      gload16(srcb + (size_t)gr * sld + k0 + offl, dst + cc * 512);
    }
    __syncthreads();
    bf16x8 af[4], bf[4];
#pragma unroll
    for (int i = 0; i < 4; ++i) {
      af[i] = ld8(&As[wr * 64 + i * 16 + lr][lg * 4]);
      bf[i] = ld8(&Bs[wc * 64 + i * 16 + lr][lg * 4]);
    }
#pragma unroll
    for (int i = 0; i < 4; ++i)
#pragma unroll
      for (int jn = 0; jn < 4; ++jn)
        acc[i][jn] = mfma16(af[i], bf[jn], acc[i][jn]);
    __syncthreads();
  }
#pragma unroll
  for (int i = 0; i < 4; ++i)
#pragma unroll
    for (int jn = 0; jn < 4; ++jn)
#pragma unroll
      for (int j = 0; j < 4; ++j) {
        int row = bm + wr * 64 + i * 16 + lg * 4 + j;
        int col = bn + wc * 64 + jn * 16 + lr;
        if (col < N) {
          if (CBF16) ((u16*)Cp)[coz * z + (size_t)row * ldc + col] = f2bf(acc[i][jn][j]);
          else ((float*)Cp)[coz * z + (size_t)row * ldc + col] = acc[i][jn][j];
        }
      }
}

// ---------------------------------------------------------------- fused per-t norms
__global__ __launch_bounds__(256) void fused_norm_kernel(
    const float* __restrict__ qkvx, const float* __restrict__ qw,
    const float* __restrict__ kvw, const float* __restrict__ gamma,
    const float* __restrict__ beta, const float2* __restrict__ tab,
    u16* __restrict__ qcb, u16* __restrict__ qch, u16* __restrict__ qcl,
    u16* __restrict__ kv_cn, u16* __restrict__ kper,
    u16* __restrict__ kih, u16* __restrict__ kil) {
  const int t = blockIdx.x, tid = threadIdx.x;
  const float* row = qkvx + (size_t)t * QKVX_;
  __shared__ float red[256];
  __shared__ float x[128];

  if (tid < 32) {
    const float* p = row + (QLR_ + KVLR_);
    float x0 = p[2 * tid], x1 = p[2 * tid + 1];
    rope_apply(tab[t * 32 + tid], x0, x1);
    kper[(size_t)t * ROPE_ + 2 * tid] = f2bf(x0);
    kper[(size_t)t * ROPE_ + 2 * tid + 1] = f2bf(x1);
  }

  float ss = 0.f;
  for (int i = tid; i < QLR_; i += 256) { float v = row[i]; ss += v * v; }
  red[tid] = ss; __syncthreads();
  for (int s = 128; s; s >>= 1) { if (tid < s) red[tid] += red[tid + s]; __syncthreads(); }
  float scl = 1.0f / sqrtf(red[0] / (float)QLR_ + EPS_);
  for (int i = tid; i < QLR_; i += 256) {
    float val = row[i] * scl * qw[i];
    qcb[(size_t)t * QLR_ + i] = f2bf(val);
    f16 h = (f16)val;
    qch[(size_t)t * QLR_ + i] = hbits(h);
    qcl[(size_t)t * QLR_ + i] = hbits((f16)(val - (float)h));
  }
  __syncthreads();

  ss = 0.f;
  for (int i = tid; i < KVLR_; i += 256) { float v = row[QLR_ + i]; ss += v * v; }
  red[tid] = ss; __syncthreads();
  for (int s = 128; s; s >>= 1) { if (tid < s) red[tid] += red[tid + s]; __syncthreads(); }
  scl = 1.0f / sqrtf(red[0] / (float)KVLR_ + EPS_);
  for (int i = tid; i < KVLR_; i += 256)
    kv_cn[(size_t)t * KVLR_ + i] = f2bf(row[QLR_ + i] * scl * kvw[i]);
  __syncthreads();

  float v = (tid < 128) ? row[QKVN_ + tid] : 0.f;
  red[tid] = v; __syncthreads();
  for (int s = 128; s; s >>= 1) { if (tid < s) red[tid] += red[tid + s]; __syncthreads(); }
  float mu = red[0] / 128.f;
  __syncthreads();
  float d = (tid < 128) ? (v - mu) : 0.f;
  red[tid] = d * d; __syncthreads();
  for (int s = 128; s; s >>= 1) { if (tid < s) red[tid] += red[tid + s]; __syncthreads(); }
  float var = red[0] / 128.f;
  if (tid < 128) x[tid] = d * (1.0f / sqrtf(var + EPS_)) * gamma[tid] + beta[tid];
  __syncthreads();
  if (tid < 32) {
    float x0 = x[2 * tid], x1 = x[2 * tid + 1];
    rope_apply(tab[t * 32 + tid], x0, x1);
    x[2 * tid] = x0; x[2 * tid + 1] = x1;
  }
  __syncthreads();
  if (tid < 128) {
    float fv = x[tid];
    f16 h = (f16)fv;
    kih[(size_t)t * IDXD_ + tid] = hbits(h);
    kil[(size_t)t * IDXD_ + tid] = hbits((f16)(fv - (float)h));
  }
}

// ---------------------------------------------------------------- rope users (table-driven)
__global__ __launch_bounds__(256) void rope_qi_split_kernel(
    const float* __restrict__ qi, const float2* __restrict__ tab,
    u16* __restrict__ qih, u16* __restrict__ qil) {
  const int t = blockIdx.x, tid = threadIdx.x;
  const float* src = qi + (size_t)t * (IDXH_ * IDXD_);
  u16* dh = qih + (size_t)t * (IDXH_ * IDXD_);
  u16* dl = qil + (size_t)t * (IDXH_ * IDXD_);
  for (int p = tid; p < IDXH_ * IDXD_ / 2; p += 256) {
    int d = p & 63;
    float x0 = src[2 * p], x1 = src[2 * p + 1];
    if (d < 32) rope_apply(tab[t * 32 + d], x0, x1);
    f16 h0 = (f16)x0, h1 = (f16)x1;
    *(u32*)(dh + 2 * p) = hpack(h0, h1);
    *(u32*)(dl + 2 * p) = hpack((f16)(x0 - (float)h0), (f16)(x1 - (float)h1));
  }
}

__global__ __launch_bounds__(256) void rope_q_bf_kernel(
    u16* __restrict__ qfb, const float2* __restrict__ tab) {
  const int t = blockIdx.x, tid = threadIdx.x;
  for (int idx = tid; idx < H_ * 32; idx += 256) {
    int hh = idx / 32, j = idx % 32;
    u16* p = qfb + (size_t)t * (H_ * QKD_) + hh * QKD_ + NOPE_ + 2 * j;
    float x0 = bf2f(p[0]), x1 = bf2f(p[1]);
    rope_apply(tab[t * 32 + j], x0, x1);
    p[0] = f2bf(x0); p[1] = f2bf(x1);
  }
}

// ---------------------------------------------------------------- indexer score (pre-split f16 MFMA)
__global__ __launch_bounds__(256) void score_mfma(
    const u16* __restrict__ qih, const u16* __restrict__ qil,
    const u16* __restrict__ kih, const u16* __restrict__ kil,
    const float* __restrict__ wgt, int ldw, float* __restrict__ score) {
  const int s0 = blockIdx.x * 64, t0 = blockIdx.y * 64;
  if (s0 > t0 + 63) return;
  __shared__ u32 Kh[64][68], Kl[64][68], Qh[64][68], Ql[64][68];
  __shared__ float wts[64][33];
  const int tid = threadIdx.x;
  const int wid = tid >> 6, lane = tid & 63, wr = wid >> 1, wc = wid & 1;
  const int lr = lane & 15, lg = lane >> 4;
#pragma unroll
  for (int j = 0; j < 4; ++j) {
    int u = tid + 256 * j; int row = u >> 4, p = u & 15;
    *(uint4*)&Kh[row][p * 4] = *(const uint4*)(kih + (size_t)(s0 + row) * IDXD_ + p * 8);
    *(uint4*)&Kl[row][p * 4] = *(const uint4*)(kil + (size_t)(s0 + row) * IDXD_ + p * 8);
  }
#pragma unroll
  for (int j = 0; j < 8; ++j) {
    int u = tid + 256 * j; int r = u >> 5, c = u & 31;
    wts[r][c] = wgt[(size_t)(t0 + r) * ldw + c];
  }
  __syncthreads();
  f16x8 bh[2][4], bl[2][4];
#pragma unroll
  for (int ni = 0; ni < 2; ++ni)
#pragma unroll
    for (int kb = 0; kb < 4; ++kb) {
      bh[ni][kb] = ldh8(&Kh[wc * 32 + ni * 16 + lr][kb * 16 + lg * 4]);
      bl[ni][kb] = ldh8(&Kl[wc * 32 + ni * 16 + lr][kb * 16 + lg * 4]);
    }
  f32x4 fin[2][2] = {};
  for (int h = 0; h < IDXH_; ++h) {
#pragma unroll
    for (int j = 0; j < 4; ++j) {
      int u = tid + 256 * j; int row = u >> 4, p = u & 15;
      size_t g = (size_t)(t0 + row) * (IDXH_ * IDXD_) + h * IDXD_ + p * 8;
      *(uint4*)&Qh[row][p * 4] = *(const uint4*)(qih + g);
      *(uint4*)&Ql[row][p * 4] = *(const uint4*)(qil + g);
    }
    __syncthreads();
    f32x4 acch[2][2] = {};
#pragma unroll
    for (int kb = 0; kb < 4; ++kb) {
      f16x8 ah0 = ldh8(&Qh[wr * 32 + lr][kb * 16 + lg * 4]);
      f16x8 ah1 = ldh8(&Qh[wr * 32 + 16 + lr][kb * 16 + lg * 4]);
      f16x8 al0 = ldh8(&Ql[wr * 32 + lr][kb * 16 + lg * 4]);
      f16x8 al1 = ldh8(&Ql[wr * 32 + 16 + lr][kb * 16 + lg * 4]);
#pragma unroll
      for (int ni = 0; ni < 2; ++ni) {
        acch[0][ni] = mfmah(ah0, bh[ni][kb], acch[0][ni]);
        acch[0][ni] = mfmah(ah0, bl[ni][kb], acch[0][ni]);
        acch[0][ni] = mfmah(al0, bh[ni][kb], acch[0][ni]);
        acch[1][ni] = mfmah(ah1, bh[ni][kb], acch[1][ni]);
        acch[1][ni] = mfmah(ah1, bl[ni][kb], acch[1][ni]);
        acch[1][ni] = mfmah(al1, bh[ni][kb], acch[1][ni]);
      }
    }
#pragma unroll
    for (int mi = 0; mi < 2; ++mi)
#pragma unroll
      for (int j = 0; j < 4; ++j) {
        float w = wts[wr * 32 + mi * 16 + lg * 4 + j][h];
        fin[mi][0][j] += w * fmaxf(acch[mi][0][j], 0.f);
        fin[mi][1][j] += w * fmaxf(acch[mi][1][j], 0.f);
      }
    __syncthreads();
  }
#pragma unroll
  for (int mi = 0; mi < 2; ++mi)
#pragma unroll
    for (int ni = 0; ni < 2; ++ni)
#pragma unroll
      for (int j = 0; j < 4; ++j) {
        int row = t0 + wr * 32 + mi * 16 + lg * 4 + j;
        int col = s0 + wc * 32 + ni * 16 + lr;
        score[(size_t)row * T_ + col] = fin[mi][ni][j];
      }
}

// ---------------------------------------------------------------- top-k (exact, 8-bit radix, parallel select)
__global__ __launch_bounds__(256) void topk_kernel(
    const float* __restrict__ score, int* __restrict__ selidx,
    int* __restrict__ selcnt) {
  const int t = blockIdx.x;
  const int L = t + 1;
  const int tid = threadIdx.x;
  if (L <= TOPK_) {
    for (int j = tid; j < TOPK_; j += 256)
      selidx[(size_t)t * TOPK_ + j] = (j < L) ? j : 0;
    if (tid == 0) selcnt[t] = L;
    return;
  }
  __shared__ unsigned u[T_];
  __shared__ unsigned hist[256];
  __shared__ unsigned sprefix;
  __shared__ int sk;
  __shared__ int part[256];
  for (int i = tid; i < T_; i += 256) {
    float v = (i < L) ? score[(size_t)t * T_ + i] : -FLT_MAX;
    unsigned b = __float_as_uint(v);
    u[i] = (b & 0x80000000u) ? ~b : (b | 0x80000000u);
  }
  if (tid == 0) { sprefix = 0u; sk = TOPK_; }
  __syncthreads();
  for (int pass = 0; pass < 4; ++pass) {
    const int shift = 24 - 8 * pass;
    hist[tid] = 0u;
    __syncthreads();
    unsigned pfx = sprefix;
    const int k = sk;
    for (int i = tid; i < L; i += 256) {
      unsigned val = u[i];
      bool match = (pass == 0) || ((val >> (shift + 8)) == pfx);
      if (match) atomicAdd(&hist[(val >> shift) & 255u], 1u);
    }
    __syncthreads();
    // parallel suffix-scan select: part[tid] = sum of hist[255-tid .. 255]
    part[tid] = (int)hist[255 - tid];
    __syncthreads();
    for (int off = 1; off < 256; off <<= 1) {
      int v = (tid >= off) ? part[tid - off] : 0;
      __syncthreads();
      part[tid] += v;
      __syncthreads();
    }
    int above = (tid > 0) ? part[tid - 1] : 0;   // count strictly above bin (255-tid)
    if (part[tid] >= k && above < k) {
      sprefix = (pfx << 8) | (unsigned)(255 - tid);
      sk = k - above;
    }
    __syncthreads();
  }
  const unsigned thr = sprefix;
  const int kEq = sk;
  const int base = tid * 8;
  int eqloc[8]; int esum = 0;
  for (int r = 0; r < 8; ++r) {
    int i = base + r;
    int f = (i < L && u[i] == thr) ? 1 : 0;
    eqloc[r] = esum; esum += f;
  }
  part[tid] = esum; __syncthreads();
  for (int off = 1; off < 256; off <<= 1) {
    int v = (tid >= off) ? part[tid - off] : 0;
    __syncthreads();
    part[tid] += v;
    __syncthreads();
  }
  const int ebase = (tid > 0) ? part[tid - 1] : 0;
  __syncthreads();
  int sloc[8], selflag[8]; int ssum = 0;
  for (int r = 0; r < 8; ++r) {
    int i = base + r;
    int f = 0;
    if (i < L) {
      unsigned ui = u[i];
      if (ui > thr) f = 1;
      else if (ui == thr && (ebase + eqloc[r]) < kEq) f = 1;
    }
    selflag[r] = f; sloc[r] = ssum; ssum += f;
  }
  part[tid] = ssum; __syncthreads();
  for (int off = 1; off < 256; off <<= 1) {
    int v = (tid >= off) ? part[tid - off] : 0;
    __syncthreads();
    part[tid] += v;
    __syncthreads();
  }
  const int sbase = (tid > 0) ? part[tid - 1] : 0;
  for (int r = 0; r < 8; ++r)
    if (selflag[r]) selidx[(size_t)t * TOPK_ + sbase + sloc[r]] = base + r;
  if (tid == 0) selcnt[t] = TOPK_;
}

// ---------------------------------------------------------------- MLA attention v8
__global__ __launch_bounds__(256, 3) void attn_mla_kernel(
    const u16* __restrict__ qeff, const u16* __restrict__ qfb,
    const u16* __restrict__ kvcn, const u16* __restrict__ kper,
    const int* __restrict__ selidx, const int* __restrict__ selcnt,
    u16* __restrict__ Olat) {
  const int t = blockIdx.x;
  const int tid = threadIdx.x;
  const int wid = tid >> 6, lane = tid & 63;
  const int lr = lane & 15, lg = lane >> 4;
  __shared__ int sidxs[512];
  __shared__ u16 Pb[16][520];
  __shared__ __align__(16) u16 SB[4][4224];  // QK: 2 x 2048-u16 bufs; PV: u32[16][132]
  __shared__ float redm[4][16];
  __shared__ float reds[4][16];
  const int cnt = selcnt[t];
  for (int j = tid; j < 512; j += 256) sidxs[j] = selidx[(size_t)t * TOPK_ + j];
  __syncthreads();

  const int kl = lane >> 2;
  const int pcs = (((lane & 3) ^ ((lane >> 3) & 3))) << 3;
  const int rsw = ((lr >> 1) & 3) << 3;
  int skey[8];
#pragma unroll
  for (int j = 0; j < 8; ++j) skey[j] = sidxs[wid * 128 + j * 16 + kl];
  u16* buf0 = &SB[wid][0];
  u16* buf1 = &SB[wid][2048];

  const u16* qe = qeff + (size_t)t * (H_ * 512) + lr * 512 + lg * 8;
  const u16* qp = qfb + (size_t)t * (H_ * QKD_) + lr * QKD_ + NOPE_ + lg * 8;
  bf16x8 qf[18];
#pragma unroll
  for (int kb = 0; kb < 16; ++kb) qf[kb] = ld8(qe + kb * 32);
  qf[16] = ld8(qp);
  qf[17] = ld8(qp + 32);

  f32x4 lgv[8] = {};
#pragma unroll
  for (int j = 0; j < 4; ++j)
    gload16(kvcn + (size_t)skey[j] * 512 + pcs, buf0 + j * 512);
#pragma unroll
  for (int j = 0; j < 4; ++j)
    gload16(kvcn + (size_t)skey[4 + j] * 512 + pcs, buf1 + j * 512);
#pragma unroll
  for (int s = 0; s < 36; ++s) {
    const int kb = s >> 1, h = s & 1;
    u16* b = (h == 0) ? buf0 : buf1;
    if (s == 35) { asm volatile("s_waitcnt vmcnt(0)" ::: "memory"); }
    else         { asm volatile("s_waitcnt vmcnt(4)" ::: "memory"); }
    __builtin_amdgcn_sched_barrier(0);
    bf16x8 kf[4];
#pragma unroll
    for (int i = 0; i < 4; ++i)
      kf[i] = ld8(b + (i * 16 + lr) * 32 + (lg * 8 ^ rsw));
#pragma unroll
    for (int i = 0; i < 4; ++i)
      lgv[h * 4 + i] = mfma16(kf[i], qf[kb], lgv[h * 4 + i]);
    asm volatile("s_waitcnt lgkmcnt(0)" ::: "memory");
    __builtin_amdgcn_sched_barrier(0);
    if (s + 2 < 36) {
      const int kb2 = (s + 2) >> 1;
      if (kb2 < 16) {
#pragma unroll
        for (int j = 0; j < 4; ++j)
          gload16(kvcn + (size_t)skey[h * 4 + j] * 512 + kb2 * 32 + pcs, b + j * 512);
      } else {
#pragma unroll
        for (int j = 0; j < 4; ++j)
          gload16(kper + (size_t)skey[h * 4 + j] * 64 + (kb2 - 16) * 32 + pcs, b + j * 512);
      }
    }
  }

  float mx = -FLT_MAX;
#pragma unroll
  for (int m = 0; m < 8; ++m)
#pragma unroll
    for (int j = 0; j < 4; ++j) {
      int slot = wid * 128 + m * 16 + lg * 4 + j;
      float v = (slot < cnt) ? lgv[m][j] * SCALING_ : -FLT_MAX;
      lgv[m][j] = v;
      mx = fmaxf(mx, v);
    }
  mx = fmaxf(mx, __shfl_xor(mx, 16));
  mx = fmaxf(mx, __shfl_xor(mx, 32));
  if (lane < 16) redm[wid][lane] = mx;
  __syncthreads();
  float hm = fmaxf(fmaxf(redm[0][lr], redm[1][lr]), fmaxf(redm[2][lr], redm[3][lr]));
  float sm = 0.f;
#pragma unroll
  for (int m = 0; m < 8; ++m)
#pragma unroll
    for (int j = 0; j < 4; ++j) {
      int slot = wid * 128 + m * 16 + lg * 4 + j;
      float e = (slot < cnt) ? expf(lgv[m][j] - hm) : 0.f;
      lgv[m][j] = e; sm += e;
    }
  sm += __shfl_xor(sm, 16);
  sm += __shfl_xor(sm, 32);
  if (lane < 16) reds[wid][lane] = sm;
  __syncthreads();
  float inv = 1.f / (reds[0][lr] + reds[1][lr] + reds[2][lr] + reds[3][lr]);
#pragma unroll
  for (int m = 0; m < 8; ++m) {
    int sl = wid * 128 + m * 16 + lg * 4;
    *(u32*)&Pb[lr][sl] = pack2(lgv[m][0] * inv, lgv[m][1] * inv);
    *(u32*)&Pb[lr][sl + 2] = pack2(lgv[m][2] * inv, lgv[m][3] * inv);
  }
  __syncthreads();

  u32* vpw = (u32*)&SB[wid][0];
  const int pl = lane >> 4;
  const int gq = lane & 15;
  const u16* vsrc = kvcn + wid * 128 + gq * 8;
  f32x4 oacc[8] = {};
  uint4 ra[4], rb[4];
#pragma unroll
  for (int s = 0; s < 4; ++s) {
    int p = s * 4 + pl;
    ra[s] = *(const uint4*)(vsrc + (size_t)sidxs[2 * p] * 512);
    rb[s] = *(const uint4*)(vsrc + (size_t)sidxs[2 * p + 1] * 512);
  }
  for (int c = 0; c < 16; ++c) {
#pragma unroll
    for (int s = 0; s < 4; ++s) {
      int p = s * 4 + pl;
      int col = (gq * 8) ^ ((s & 3) << 3);
      const u16* A = (const u16*)&ra[s];
      const u16* B = (const u16*)&rb[s];
      u32 w[8];
#pragma unroll
      for (int j = 0; j < 8; ++j) w[j] = (u32)A[j] | ((u32)B[j] << 16);
      *(uint4*)&vpw[p * 132 + col] = make_uint4(w[0], w[1], w[2], w[3]);
      *(uint4*)&vpw[p * 132 + col + 4] = make_uint4(w[4], w[5], w[6], w[7]);
    }
    if (c < 15) {
#pragma unroll
      for (int s = 0; s < 4; ++s) {
        int p = s * 4 + pl;
        ra[s] = *(const uint4*)(vsrc + (size_t)sidxs[(c + 1) * 32 + 2 * p] * 512);
        rb[s] = *(const uint4*)(vsrc + (size_t)sidxs[(c + 1) * 32 + 2 * p + 1] * 512);
      }
    }
    bf16x8 pa = ld8(&Pb[lr][c * 32 + lg * 8]);
    union BB { u32 u[4]; bf16x8 v; };
    BB bb[8];
#pragma unroll
    for (int C = 0; C < 8; ++C) {
      int col = (C * 16 + lr) ^ (lg << 3);
#pragma unroll
      for (int e = 0; e < 4; ++e)
        bb[C].u[e] = vpw[(lg * 4 + e) * 132 + col];
    }
    __builtin_amdgcn_s_setprio(1);
#pragma unroll
    for (int C = 0; C < 8; ++C) oacc[C] = mfma16(pa, bb[C].v, oacc[C]);
    __builtin_amdgcn_s_setprio(0);
  }
#pragma unroll
  for (int C = 0; C < 8; ++C)
#pragma unroll
    for (int j = 0; j < 4; ++j) {
      int h = lg * 4 + j;
      Olat[(size_t)t * (H_ * 512) + h * 512 + wid * 128 + C * 16 + lr] = f2bf(oacc[C][j]);
    }
}

// ---------------------------------------------------------------- launch
extern "C" void kernel_launch(void* const* d_in, const int* in_sizes, int n_in,
                              void* d_out, int out_size, void* d_ws, size_t ws_size,
                              hipStream_t stream) {
  const float* hidden    = (const float*)d_in[1];
  const float* w_qkv_a   = (const float*)d_in[2];
  const float* q_a_ln_w  = (const float*)d_in[3];
  const float* w_qb      = (const float*)d_in[4];
  const float* kv_a_ln_w = (const float*)d_in[5];
  const float* w_kvb     = (const float*)d_in[6];
  const float* w_o       = (const float*)d_in[7];
  const float* w_idx_qb  = (const float*)d_in[8];
  const float* w_idx_k   = (const float*)d_in[9];
  const float* idx_g     = (const float*)d_in[10];
  const float* idx_b     = (const float*)d_in[11];
  const float* w_wproj   = (const float*)d_in[12];
  const float* b_wproj   = (const float*)d_in[13];

  char* W = (char*)d_ws;
  size_t o = 0;
  auto alloc = [&](size_t bytes) { void* p = W + o; o += (bytes + 255) & ~(size_t)255; return p; };
  u16* qcb     = (u16*)alloc((size_t)T_ * QLR_ * 2);
  u16* kv_cn   = (u16*)alloc((size_t)T_ * KVLR_ * 2);
  u16* kper    = (u16*)alloc((size_t)T_ * ROPE_ * 2);
  int* selidx  = (int*)alloc((size_t)T_ * TOPK_ * 4);
  int* selcnt  = (int*)alloc((size_t)T_ * 4);
  u16* kih     = (u16*)alloc((size_t)T_ * IDXD_ * 2);
  u16* kil     = (u16*)alloc((size_t)T_ * IDXD_ * 2);
  u16* hidh    = (u16*)alloc((size_t)T_ * HID_ * 2);
  u16* hidl    = (u16*)alloc((size_t)T_ * HID_ * 2);
  float2* rtab = (float2*)alloc((size_t)T_ * 32 * 8);
  u16* qch     = (u16*)alloc((size_t)T_ * QLR_ * 2);
  u16* qcl     = (u16*)alloc((size_t)T_ * QLR_ * 2);
  u16* wiqh    = (u16*)alloc((size_t)(IDXH_ * IDXD_) * QLR_ * 2);
  u16* wiql    = (u16*)alloc((size_t)(IDXH_ * IDXD_) * QLR_ * 2);
  u16* qih     = qch;
  u16* qil     = qch + (size_t)T_ * IDXH_ * IDXD_;
  float* qi    = (float*)alloc((size_t)T_ * IDXH_ * IDXD_ * 4);
  u16* qeff    = (u16*)qi;
  float* score = (float*)alloc((size_t)T_ * T_ * 4);
  u16* qfb     = (u16*)score;
  u16* attno   = (u16*)score;
  u16* wcath   = (u16*)alloc((size_t)QKVX_ * HID_ * 2);
  u16* wcatl   = (u16*)alloc((size_t)QKVX_ * HID_ * 2);
  float* qkvx  = (float*)alloc((size_t)T_ * QKVX_ * 4);
  u16* Olat    = wcath;
  u16* wqbt    = (u16*)alloc((size_t)(H_ * QKD_) * QLR_ * 2);
  u16* wkvb    = (u16*)alloc((size_t)KVLR_ * (H_ * 256) * 2);
  u16* wkvbt   = (u16*)alloc((size_t)(H_ * 256) * KVLR_ * 2);
  u16* wot     = (u16*)alloc((size_t)(H_ * VD_) * HID_ * 2);

  dim3 blk(256);
  auto g2 = [](int M, int N, int Z) { return dim3((N + 127) / 128, M / 128, Z); };

  prep_elem_multi<<<dim3(1024, 1, 3), blk, 0, stream>>>(
      rtab, hidden, hidh, hidl, w_kvb, wkvb);
  {
    TSJob j0{w_qkv_a, wcath, wcatl, HID_, QKVN_};
    TSJob j1{w_idx_qb, wiqh, wiql, QLR_, IDXH_ * IDXD_};
    TSJob j2{w_idx_k, wcath + (size_t)QKVN_ * HID_, wcatl + (size_t)QKVN_ * HID_, HID_, IDXD_};
    TSJob j3{w_wproj, wcath + (size_t)(QKVN_ + IDXD_) * HID_, wcatl + (size_t)(QKVN_ + IDXD_) * HID_, HID_, IDXH_};
    transpose_split_multi<<<dim3(64, 32, 4), blk, 0, stream>>>(j0, j1, j2, j3);
  }
  {
    TBJob j0{w_qb, wqbt, QLR_, H_ * QKD_};
    TBJob j1{w_kvb, wkvbt, KVLR_, H_ * 256};
    TBJob j2{w_o, wot, H_ * VD_, HID_};
    transpose_bf16_multi<<<dim3(64, 32, 3), blk, 0, stream>>>(j0, j1, j2);
  }

  gemm_hl<<<g2(T_, QKVX_, 1), blk, 0, stream>>>(
      hidh, hidl, HID_, wcath, wcatl, HID_, qkvx, QKVX_,
      b_wproj, QKVN_ + IDXD_, 0.015625f, QKVX_, HID_);
  fused_norm_kernel<<<T_, blk, 0, stream>>>(
      qkvx, q_a_ln_w, kv_a_ln_w, idx_g, idx_b, rtab,
      qcb, qch, qcl, kv_cn, kper, kih, kil);

  gemm_hl<<<g2(T_, IDXH_ * IDXD_, 1), blk, 0, stream>>>(
      qch, qcl, QLR_, wiqh, wiql, QLR_, qi, IDXH_ * IDXD_,
      nullptr, 1 << 30, 1.f, IDXH_ * IDXD_, QLR_);
  rope_qi_split_kernel<<<T_, blk, 0, stream>>>(qi, rtab, qih, qil);

  score_mfma<<<dim3(32, 32), blk, 0, stream>>>(qih, qil, kih, kil,
                                               qkvx + QKVN_ + IDXD_, QKVX_, score);
  topk_kernel<<<T_, blk, 0, stream>>>(score, selidx, selcnt);

  gemm_t<1><<<g2(T_, H_ * QKD_, 1), blk, 0, stream>>>(qcb, QLR_, 0, wqbt, QLR_, 0, qfb, H_ * QKD_, 0, H_ * QKD_, QLR_);
  rope_q_bf_kernel<<<T_, blk, 0, stream>>>(qfb, rtab);
  gemm_t<1><<<g2(T_, 512, H_), blk, 0, stream>>>(qfb, H_ * QKD_, QKD_, wkvb, H_ * 256, 256, qeff, H_ * 512, 512, 512, NOPE_);
  attn_mla_kernel<<<T_, blk, 0, stream>>>(qeff, qfb, kv_cn, kper, selidx, selcnt, Olat);
  gemm_t<1><<<g2(T_, VD_, H_), blk, 0, stream>>>(Olat, H_ * 512, 512, wkvbt + 128 * 512, KVLR_, 256 * 512, attno, H_ * VD_, VD_, VD_, 512);
  gemm_t<0><<<g2(T_, HID_, 1), blk, 0, stream>>>(attno, H_ * VD_, 0, wot, H_ * VD_, 0, d_out, HID_, 0, HID_, H_ * VD_);
}